// Round 10
// baseline (1228.143 us; speedup 1.0000x reference)
//
#include <hip/hip_runtime.h>

typedef __attribute__((ext_vector_type(8))) short short8;
typedef __attribute__((ext_vector_type(4))) short bf16x4;
typedef __attribute__((ext_vector_type(4))) float f32x4;

#define DEV __device__ __forceinline__

DEV unsigned short f2bf(float f) {
    unsigned int u = __builtin_bit_cast(unsigned int, f);
    u += 0x7fffu + ((u >> 16) & 1u);
    return (unsigned short)(u >> 16);
}

#define GLOAD16(gp, lp)                                                        \
    __builtin_amdgcn_global_load_lds(                                          \
        (const __attribute__((address_space(1))) void*)(gp),                   \
        (__attribute__((address_space(3))) void*)(lp), 16, 0, 0)

// ------------------------------------------------------------- ln_bf16 ----
__global__ __launch_bounds__(256) void ln_bf16(
    const float* __restrict__ hidden, const float* __restrict__ inputs,
    const float* __restrict__ ln1w, const float* __restrict__ ln1b,
    const float* __restrict__ ln2w, const float* __restrict__ ln2b,
    unsigned short* __restrict__ LNh, unsigned short* __restrict__ LNx)
{
    int row = blockIdx.x * 4 + (threadIdx.x >> 6);
    int lane = threadIdx.x & 63;
    const float *src, *wp, *bp; unsigned short* dst;
    if (row < 4096) { src = hidden + (size_t)row * 1024; wp = ln1w; bp = ln1b; dst = LNh + (size_t)row * 1024; }
    else { int r = row - 4096; src = inputs + (size_t)r * 1024; wp = ln2w; bp = ln2b; dst = LNx + (size_t)r * 1024; }

    f32x4 v[4];
    float s = 0.f, ss = 0.f;
#pragma unroll
    for (int i = 0; i < 4; ++i) {
        v[i] = *reinterpret_cast<const f32x4*>(src + i * 256 + lane * 4);
#pragma unroll
        for (int j = 0; j < 4; ++j) { s += v[i][j]; ss += v[i][j] * v[i][j]; }
    }
#pragma unroll
    for (int off = 32; off >= 1; off >>= 1) { s += __shfl_xor(s, off); ss += __shfl_xor(ss, off); }
    float mu = s * (1.f / 1024.f);
    float var = fmaxf(ss * (1.f / 1024.f) - mu * mu, 0.f);
    float rs = rsqrtf(var + 1e-5f);
#pragma unroll
    for (int i = 0; i < 4; ++i) {
        f32x4 wv = *reinterpret_cast<const f32x4*>(wp + i * 256 + lane * 4);
        f32x4 bv = *reinterpret_cast<const f32x4*>(bp + i * 256 + lane * 4);
        bf16x4 o;
#pragma unroll
        for (int j = 0; j < 4; ++j) o[j] = (short)f2bf((v[i][j] - mu) * rs * wv[j] + bv[j]);
        *reinterpret_cast<bf16x4*>(dst + i * 256 + lane * 4) = o;
    }
}

// ------------------------------------------------------------- convert ----
__global__ __launch_bounds__(256) void convert_w(
    const float* __restrict__ Wq, const float* __restrict__ Wk, const float* __restrict__ Wv,
    unsigned short* __restrict__ oq, unsigned short* __restrict__ ok_, unsigned short* __restrict__ ov)
{
    unsigned tid = blockIdx.x * 256 + threadIdx.x;
    int arr = tid >> 17;
    size_t off = (size_t)(tid & 131071u) * 8;
    const float* s = (arr == 0) ? Wq : (arr == 1) ? Wk : Wv;
    unsigned short* d = (arr == 0) ? oq : (arr == 1) ? ok_ : ov;
    f32x4 a = *reinterpret_cast<const f32x4*>(s + off);
    f32x4 b = *reinterpret_cast<const f32x4*>(s + off + 4);
    short8 r;
#pragma unroll
    for (int j = 0; j < 4; ++j) { r[j] = (short)f2bf(a[j]); r[j + 4] = (short)f2bf(b[j]); }
    *reinterpret_cast<short8*>(d + off) = r;
}

// --------------------------------------------- gemm_bt (Q projection) ----
__global__ __launch_bounds__(256) void gemm_bt(
    const unsigned short* __restrict__ A,
    const unsigned short* __restrict__ W, const float* __restrict__ bias,
    unsigned short* __restrict__ C)
{
    __shared__ __align__(16) unsigned short smem[16384];
    unsigned short* As = smem;
    unsigned short* Bs = smem + 8192;

    int t = threadIdx.x, lane = t & 63, w = t >> 6;
    int wr = w >> 1, wc = w & 1, g = lane >> 4, lr = lane & 15;
    int m0 = blockIdx.x * 128;
    int n0 = blockIdx.y * 128;

    f32x4 acc[4][4];
#pragma unroll
    for (int i = 0; i < 4; ++i)
#pragma unroll
        for (int j = 0; j < 4; ++j) acc[i][j] = (f32x4)0.f;

    int srow = lane >> 3;
    int scb  = (lane & 7) * 16;

    for (int kb = 0; kb < 1024; kb += 64) {
#pragma unroll
        for (int i = 0; i < 4; ++i) {
            int row = i * 32 + w * 8 + srow;
            int cb = scb ^ ((row & 7) << 4);
            const char* ga = (const char*)(A + (size_t)(m0 + row) * 1024 + kb) + cb;
            GLOAD16(ga, &As[(size_t)(i * 32 + w * 8) * 64]);
            const char* gb = (const char*)(W + (size_t)(n0 + row) * 1024 + kb) + cb;
            GLOAD16(gb, &Bs[(size_t)(i * 32 + w * 8) * 64]);
        }
        __syncthreads();
#pragma unroll
        for (int kk = 0; kk < 2; ++kk) {
            int cb0 = kk * 64 + g * 16;
            short8 af[4], bf[4];
#pragma unroll
            for (int mi = 0; mi < 4; ++mi) {
                int row = wr * 64 + mi * 16 + lr;
                af[mi] = *reinterpret_cast<const short8*>(
                    (const char*)As + row * 128 + (cb0 ^ ((row & 7) << 4)));
            }
#pragma unroll
            for (int ni = 0; ni < 4; ++ni) {
                int row = wc * 64 + ni * 16 + lr;
                bf[ni] = *reinterpret_cast<const short8*>(
                    (const char*)Bs + row * 128 + (cb0 ^ ((row & 7) << 4)));
            }
#pragma unroll
            for (int mi = 0; mi < 4; ++mi)
#pragma unroll
                for (int ni = 0; ni < 4; ++ni)
                    acc[mi][ni] = __builtin_amdgcn_mfma_f32_16x16x32_bf16(af[mi], bf[ni], acc[mi][ni], 0, 0, 0);
        }
        __syncthreads();
    }

    unsigned short* Ct = smem;
#pragma unroll
    for (int ni = 0; ni < 4; ++ni) {
        int coll = wc * 64 + ni * 16 + lr;
        float bv = bias[n0 + coll];
#pragma unroll
        for (int mi = 0; mi < 4; ++mi)
#pragma unroll
            for (int j = 0; j < 4; ++j) {
                int rowl = wr * 64 + mi * 16 + g * 4 + j;
                Ct[rowl * 128 + coll] = f2bf(acc[mi][ni][j] + bv);
            }
    }
    __syncthreads();
#pragma unroll
    for (int i = 0; i < 8; ++i) {
        int idx = i * 2048 + t * 8;
        int row = idx >> 7, col = idx & 127;
        *reinterpret_cast<short8*>(C + (size_t)(m0 + row) * 1024 + n0 + col) =
            *reinterpret_cast<const short8*>(&Ct[idx]);
    }
}

// ------------------------------------------- gemm256 (BK=32, 2 blk/CU) ----
// Same phase schedule as round 8, but slots hold a 32-wide K-tile:
// LDS = 2 slots x (A 16KB + B 16KB) = 64KB -> 2 blocks/CU, 16 waves/CU.
// A/B tiles have 64B rows; swizzle is a 4-slot XOR (uniform bank-quad spread).
// Per phase: {8 ds_read ; 2 gload stage ; barrier ; lgkmcnt(0) ; 16 MFMA ;
//             [K-tile end: vmcnt(0)] ; barrier}. 64 phases total.
__global__ __launch_bounds__(512, 4) void gemm256(
    const unsigned short* __restrict__ A, const unsigned short* __restrict__ W,
    const float* __restrict__ b0, const float* __restrict__ b1,
    unsigned short* __restrict__ Cn, unsigned short* __restrict__ Vt,
    int mtiles, int tsplit)
{
    __shared__ __align__(16) char smemc[65536];   // A slots @0,16384; B @32768,49152

    int t = threadIdx.x, lane = t & 63, w = t >> 6, g = lane >> 4, lr = lane & 15;
    int wr = w >> 2, wcn = w & 3;
    int R0 = wr * 128, C0 = wcn * 64;

    int id = blockIdx.x;
    int ntc = gridDim.x / mtiles;              // n-tiles (8)
    int xcd = id & 7, ord = id >> 3;           // hw dispatch: id%8 -> XCD
    int mt = xcd * (mtiles >> 3) + ord / ntc;  // contiguous mt chunk per XCD
    int nt = ord % ntc;                        // nt fastest: A-panel L2 reuse
    int m0 = mt * 256, n0 = nt * 256;

    const unsigned short* Ap = A + (size_t)m0 * 1024;
    const unsigned short* Wp = W + (size_t)n0 * 1024;

    f32x4 acc[8][4];
#pragma unroll
    for (int i = 0; i < 8; ++i)
#pragma unroll
        for (int j = 0; j < 4; ++j) acc[i][j] = (f32x4)0.f;

    int srl = lane >> 2;                               // row 0..15 within gload
    int ssl = ((lane & 3) ^ ((lane >> 3) & 3)) * 16;   // pre-swizzled src slot

    // stage rows [p*128 + w*16, +16) of A and B for K-tile kt into slot
    auto STAGE2 = [&](int slot, int kt, int p) {
        int rl = p * 128 + w * 16;
        int r = rl + srl;
        const char* ga = (const char*)Ap + (size_t)r * 2048 + kt * 64 + ssl;
        GLOAD16(ga, smemc + slot * 16384 + rl * 64);
        const char* gb = (const char*)Wp + (size_t)r * 2048 + kt * 64 + ssl;
        GLOAD16(gb, smemc + 32768 + slot * 16384 + rl * 64);
    };

    // prologue: K-tile 0 -> slot 0
    STAGE2(0, 0, 0); STAGE2(0, 0, 1);
    asm volatile("s_waitcnt vmcnt(0)" ::: "memory");
    __builtin_amdgcn_s_barrier();

    int swz = (g ^ ((lr >> 1) & 3)) << 4;              // read-side slot byte

    for (int kt = 0; kt < 32; ++kt) {
        const int cs = kt & 1;
        const char* Ab = smemc + cs * 16384;
        const char* Bb = smemc + 32768 + cs * 16384;
#pragma unroll
        for (int mq = 0; mq < 2; ++mq) {
            short8 af[4], bfv[4];
#pragma unroll
            for (int a = 0; a < 4; ++a) {
                int r = R0 + (mq * 4 + a) * 16 + lr;
                af[a] = *reinterpret_cast<const short8*>(Ab + r * 64 + swz);
            }
#pragma unroll
            for (int ni = 0; ni < 4; ++ni) {
                int r = C0 + ni * 16 + lr;
                bfv[ni] = *reinterpret_cast<const short8*>(Bb + r * 64 + swz);
            }
            if (kt < 31) STAGE2(cs ^ 1, kt + 1, mq);
            __builtin_amdgcn_sched_barrier(0);
            __builtin_amdgcn_s_barrier();
            asm volatile("s_waitcnt lgkmcnt(0)" ::: "memory");
            __builtin_amdgcn_sched_barrier(0);
            __builtin_amdgcn_s_setprio(1);
#pragma unroll
            for (int a = 0; a < 4; ++a)
#pragma unroll
                for (int ni = 0; ni < 4; ++ni)
                    acc[mq * 4 + a][ni] =
                        __builtin_amdgcn_mfma_f32_16x16x32_bf16(af[a], bfv[ni], acc[mq * 4 + a][ni], 0, 0, 0);
            __builtin_amdgcn_s_setprio(0);
            if (mq == 1) asm volatile("s_waitcnt vmcnt(0)" ::: "memory");
            __builtin_amdgcn_sched_barrier(0);
            __builtin_amdgcn_s_barrier();
        }
    }
    __syncthreads();

    unsigned short* CtS = (unsigned short*)smemc;      // [64][272] = 34.8KB
    if (nt < tsplit) {
#pragma unroll
        for (int ch = 0; ch < 4; ++ch) {
            if (ch) __syncthreads();
            if (wr == (ch >> 1)) {
                int ma = (ch & 1) * 4;
#pragma unroll
                for (int ni = 0; ni < 4; ++ni) {
                    int c = C0 + ni * 16 + lr;
                    float bvv = b0[n0 + c];
#pragma unroll
                    for (int a = 0; a < 4; ++a)
#pragma unroll
                        for (int j = 0; j < 4; ++j)
                            CtS[(a * 16 + g * 4 + j) * 272 + c] = f2bf(acc[ma + a][ni][j] + bvv);
                }
            }
            __syncthreads();
#pragma unroll
            for (int it = 0; it < 4; ++it) {
                int u2 = it * 512 + t;
                int row = u2 >> 5, c16 = u2 & 31;
                *reinterpret_cast<short8*>(Cn + (size_t)(m0 + ch * 64 + row) * 1024 + n0 + c16 * 8) =
                    *reinterpret_cast<const short8*>(&CtS[row * 272 + c16 * 8]);
            }
        }
    } else {
        int hbase = (nt - tsplit) * 2;
        int b = m0 >> 12, kv0 = m0 & 4095;
#pragma unroll
        for (int ch = 0; ch < 4; ++ch) {
            if (ch) __syncthreads();
            if (wcn == ch) {
#pragma unroll
                for (int ni = 0; ni < 4; ++ni) {
                    int dl = ni * 16 + lr;             // d within 64-chunk
                    float bvv = b1[(nt - tsplit) * 256 + ch * 64 + dl];
#pragma unroll
                    for (int mi = 0; mi < 8; ++mi)
#pragma unroll
                        for (int j = 0; j < 4; ++j)
                            CtS[dl * 272 + wr * 128 + mi * 16 + g * 4 + j] = f2bf(acc[mi][ni][j] + bvv);
                }
            }
            __syncthreads();
            unsigned short* dst = Vt + ((size_t)(b * 8 + hbase + (ch >> 1)) * 128 + (ch & 1) * 64) * 4096 + kv0;
#pragma unroll
            for (int it = 0; it < 4; ++it) {
                int u2 = it * 512 + t;
                int row = u2 >> 5, c16 = u2 & 31;
                *reinterpret_cast<short8*>(dst + (size_t)row * 4096 + c16 * 8) =
                    *reinterpret_cast<const short8*>(&CtS[row * 272 + c16 * 8]);
            }
        }
    }
}

// ----------------------------------------------------------- attention ----
// unchanged (verified): swapped QK^T, defer-max, packed P, dbuf gload_lds.
__global__ __launch_bounds__(256, 2) void attn_kernel(
    const unsigned short* __restrict__ Qm, const unsigned short* __restrict__ Km,
    const unsigned short* __restrict__ VtG, const float* __restrict__ hidden,
    float* __restrict__ out)
{
    __shared__ __align__(16) unsigned short Kl[2][64 * 128];
    __shared__ __align__(16) unsigned short Vt[2][128 * 64];
    __shared__ __align__(16) unsigned short Pl[64 * 64];

    int t = threadIdx.x, lane = t & 63, w = t >> 6, g = lane >> 4, lr = lane & 15;
    int id = blockIdx.x;
    int swz = (id & 7) * 64 + (id >> 3);
    int qt = swz & 7, h = (swz >> 3) & 7, b = swz >> 6;

    short8 qf[4];
#pragma unroll
    for (int kk = 0; kk < 4; ++kk)
        qf[kk] = *reinterpret_cast<const short8*>(
            Qm + (size_t)(b * 512 + qt * 64 + w * 16 + lr) * 1024 + h * 128 + kk * 32 + g * 8);
    asm volatile("s_waitcnt vmcnt(0)" ::: "memory");

    float m2 = 0.f;
    float l = 0.f;
    f32x4 oacc[8];
#pragma unroll
    for (int nf = 0; nf < 8; ++nf) oacc[nf] = (f32x4)0.f;

    const float SCALE = 0.08838834764831845f;
    const float LOG2E = 1.4426950408889634f;
    const float K1 = SCALE * LOG2E;
    const float THR2 = 11.5f;

    size_t kbase = (size_t)b * 4096 * 1024 + h * 128;
    size_t vbase = ((size_t)(b * 8 + h)) * 128 * 4096;

    auto STAGE_K = [&](int buf, int c) {
        int kv0 = c * 64;
#pragma unroll
        for (int i = 0; i < 4; ++i) {
            int rb = w * 16 + i * 4;
            int row = rb + (lane >> 4);
            int cb = ((lane & 15) * 16) ^ ((row & 7) << 4);
            const char* gp = (const char*)(Km + kbase + (size_t)(kv0 + row) * 1024) + cb;
            GLOAD16(gp, &Kl[buf][rb * 128]);
        }
    };
    auto STAGE_V = [&](int buf, int c) {
        int kv0 = c * 64;
#pragma unroll
        for (int i = 0; i < 4; ++i) {
            int db = w * 32 + i * 8;
            int d = db + (lane >> 3);
            int cb = ((lane & 7) * 16) ^ ((d & 7) << 4);
            const char* gp = (const char*)(VtG + vbase + (size_t)d * 4096 + kv0) + cb;
            GLOAD16(gp, &Vt[buf][db * 64]);
        }
    };

    STAGE_K(0, 0); STAGE_V(0, 0);

    for (int c = 0; c < 64; ++c) {
        int cur = c & 1;
        asm volatile("s_waitcnt vmcnt(0) lgkmcnt(0)" ::: "memory");
        __builtin_amdgcn_sched_barrier(0);
        __builtin_amdgcn_s_barrier();
        if (c < 63) { STAGE_K(cur ^ 1, c + 1); STAGE_V(cur ^ 1, c + 1); }

        f32x4 sacc[4];
#pragma unroll
        for (int nf = 0; nf < 4; ++nf) sacc[nf] = (f32x4)0.f;
#pragma unroll
        for (int kk = 0; kk < 4; ++kk) {
            int cb0 = kk * 64 + g * 16;
            short8 kf[4];
#pragma unroll
            for (int nf = 0; nf < 4; ++nf) {
                int row = nf * 16 + lr;
                kf[nf] = *reinterpret_cast<const short8*>(
                    (const char*)&Kl[cur][0] + row * 256 + (cb0 ^ ((row & 7) << 4)));
            }
            __builtin_amdgcn_s_setprio(1);
#pragma unroll
            for (int nf = 0; nf < 4; ++nf)
                sacc[nf] = __builtin_amdgcn_mfma_f32_16x16x32_bf16(kf[nf], qf[kk], sacc[nf], 0, 0, 0);
            __builtin_amdgcn_s_setprio(0);
        }

        float smax = sacc[0][0];
#pragma unroll
        for (int nf = 0; nf < 4; ++nf)
#pragma unroll
            for (int j = 0; j < 4; ++j) smax = fmaxf(smax, sacc[nf][j]);
        float s2max = smax * K1;
        if (!__all(s2max <= m2 + THR2)) {
            float rm = s2max;
            rm = fmaxf(rm, __shfl_xor(rm, 16));
            rm = fmaxf(rm, __shfl_xor(rm, 32));
            float m2n = fmaxf(m2, rm);
            float corr = exp2f(m2 - m2n);
            l *= corr;
            m2 = m2n;
#pragma unroll
            for (int j = 0; j < 4; ++j) {
                float cj = __shfl(corr, g * 4 + j);
#pragma unroll
                for (int nf = 0; nf < 8; ++nf) oacc[nf][j] *= cj;
            }
        }
        int prow = w * 16 + lr;
        int rsw = (lr & 7) << 4;
#pragma unroll
        for (int nf = 0; nf < 4; ++nf) {
            float p0 = exp2f(sacc[nf][0] * K1 - m2);
            float p1 = exp2f(sacc[nf][1] * K1 - m2);
            float p2 = exp2f(sacc[nf][2] * K1 - m2);
            float p3 = exp2f(sacc[nf][3] * K1 - m2);
            l += (p0 + p1) + (p2 + p3);
            bf16x4 pk;
            pk[0] = (short)f2bf(p0); pk[1] = (short)f2bf(p1);
            pk[2] = (short)f2bf(p2); pk[3] = (short)f2bf(p3);
            *reinterpret_cast<bf16x4*>(
                (char*)Pl + prow * 128 + ((nf * 32 + g * 8) ^ rsw)) = pk;
        }
        asm volatile("s_waitcnt lgkmcnt(0)" ::: "memory");
        __builtin_amdgcn_sched_barrier(0);

#pragma unroll
        for (int kp = 0; kp < 2; ++kp) {
            int cb0 = kp * 64 + g * 16;
            short8 pa = *reinterpret_cast<const short8*>(
                (const char*)Pl + prow * 128 + (cb0 ^ rsw));
#pragma unroll
            for (int nf = 0; nf < 8; ++nf) {
                int d = nf * 16 + lr;
                short8 vb = *reinterpret_cast<const short8*>(
                    (const char*)&Vt[cur][0] + d * 128 + (cb0 ^ ((d & 7) << 4)));
                oacc[nf] = __builtin_amdgcn_mfma_f32_16x16x32_bf16(pa, vb, oacc[nf], 0, 0, 0);
            }
        }
    }

    l += __shfl_xor(l, 16);
    l += __shfl_xor(l, 32);
#pragma unroll
    for (int j = 0; j < 4; ++j) {
        float lj = __shfl(l, g * 4 + j);
        float inv = 1.f / lj;
        int q = qt * 64 + w * 16 + g * 4 + j;
        size_t base = (size_t)(b * 512 + q) * 1024 + h * 128;
#pragma unroll
        for (int nf = 0; nf < 8; ++nf) {
            int d = nf * 16 + lr;
            out[base + d] = hidden[base + d] + oacc[nf][j] * inv;
        }
    }
}

// ---------------------------------------------------------------- host ----
extern "C" void kernel_launch(void* const* d_in, const int* in_sizes, int n_in,
                              void* d_out, int out_size, void* d_ws, size_t ws_size,
                              hipStream_t stream) {
    const float* hidden = (const float*)d_in[0];
    const float* inputs = (const float*)d_in[1];
    const float* ln1w   = (const float*)d_in[2];
    const float* ln1b   = (const float*)d_in[3];
    const float* ln2w   = (const float*)d_in[4];
    const float* ln2b   = (const float*)d_in[5];
    const float* Wq     = (const float*)d_in[6];
    const float* bq     = (const float*)d_in[7];
    const float* Wk     = (const float*)d_in[8];
    const float* bk     = (const float*)d_in[9];
    const float* Wv     = (const float*)d_in[10];
    const float* bv     = (const float*)d_in[11];
    float* out = (float*)d_out;
    char* ws = (char*)d_ws;

    unsigned short* LNh = (unsigned short*)ws;        // 4096x1024 bf16
    unsigned short* LNx = LNh + 4194304;              // 32768x1024
    unsigned short* WqB = LNx + 33554432;             // Wq, then Wk|Wv contiguous
    unsigned short* WkB = WqB + 1048576;
    unsigned short* WvB = WkB + 1048576;
    unsigned short* Qm  = WvB + 1048576;              // 4096x1024
    unsigned short* Km  = Qm + 4194304;               // 32768x1024
    unsigned short* VtG = Km + 33554432;              // [b][h][128 d][4096 kv]

    ln_bf16<<<dim3(9216), dim3(256), 0, stream>>>(hidden, inputs, ln1w, ln1b, ln2w, ln2b, LNh, LNx);
    convert_w<<<dim3(1536), dim3(256), 0, stream>>>(Wq, Wk, Wv, WqB, WkB, WvB);
    gemm_bt<<<dim3(32, 8), dim3(256), 0, stream>>>(LNh, WqB, bq, Qm);
    gemm256<<<dim3(1024), dim3(512), 0, stream>>>(LNx, WkB, bk, bv, Km, VtG, 128, 4);
    attn_kernel<<<dim3(512), dim3(256), 0, stream>>>(Qm, Km, VtG, hidden, out);
}

// Round 11
// 350.124 us; speedup vs baseline: 3.5077x; 3.5077x over previous
//
#include <hip/hip_runtime.h>

typedef __attribute__((ext_vector_type(8))) short short8;
typedef __attribute__((ext_vector_type(4))) short bf16x4;
typedef __attribute__((ext_vector_type(4))) float f32x4;

#define DEV __device__ __forceinline__

DEV unsigned short f2bf(float f) {
    unsigned int u = __builtin_bit_cast(unsigned int, f);
    u += 0x7fffu + ((u >> 16) & 1u);
    return (unsigned short)(u >> 16);
}

#define GLOAD16(gp, lp)                                                        \
    __builtin_amdgcn_global_load_lds(                                          \
        (const __attribute__((address_space(1))) void*)(gp),                   \
        (__attribute__((address_space(3))) void*)(lp), 16, 0, 0)

// ------------------------------------------------------------- ln_bf16 ----
__global__ __launch_bounds__(256) void ln_bf16(
    const float* __restrict__ hidden, const float* __restrict__ inputs,
    const float* __restrict__ ln1w, const float* __restrict__ ln1b,
    const float* __restrict__ ln2w, const float* __restrict__ ln2b,
    unsigned short* __restrict__ LNh, unsigned short* __restrict__ LNx)
{
    int row = blockIdx.x * 4 + (threadIdx.x >> 6);
    int lane = threadIdx.x & 63;
    const float *src, *wp, *bp; unsigned short* dst;
    if (row < 4096) { src = hidden + (size_t)row * 1024; wp = ln1w; bp = ln1b; dst = LNh + (size_t)row * 1024; }
    else { int r = row - 4096; src = inputs + (size_t)r * 1024; wp = ln2w; bp = ln2b; dst = LNx + (size_t)r * 1024; }

    f32x4 v[4];
    float s = 0.f, ss = 0.f;
#pragma unroll
    for (int i = 0; i < 4; ++i) {
        v[i] = *reinterpret_cast<const f32x4*>(src + i * 256 + lane * 4);
#pragma unroll
        for (int j = 0; j < 4; ++j) { s += v[i][j]; ss += v[i][j] * v[i][j]; }
    }
#pragma unroll
    for (int off = 32; off >= 1; off >>= 1) { s += __shfl_xor(s, off); ss += __shfl_xor(ss, off); }
    float mu = s * (1.f / 1024.f);
    float var = fmaxf(ss * (1.f / 1024.f) - mu * mu, 0.f);
    float rs = rsqrtf(var + 1e-5f);
#pragma unroll
    for (int i = 0; i < 4; ++i) {
        f32x4 wv = *reinterpret_cast<const f32x4*>(wp + i * 256 + lane * 4);
        f32x4 bv = *reinterpret_cast<const f32x4*>(bp + i * 256 + lane * 4);
        bf16x4 o;
#pragma unroll
        for (int j = 0; j < 4; ++j) o[j] = (short)f2bf((v[i][j] - mu) * rs * wv[j] + bv[j]);
        *reinterpret_cast<bf16x4*>(dst + i * 256 + lane * 4) = o;
    }
}

// ------------------------------------------------------------- convert ----
__global__ __launch_bounds__(256) void convert_w(
    const float* __restrict__ Wq, const float* __restrict__ Wk, const float* __restrict__ Wv,
    unsigned short* __restrict__ oq, unsigned short* __restrict__ ok_, unsigned short* __restrict__ ov)
{
    unsigned tid = blockIdx.x * 256 + threadIdx.x;
    int arr = tid >> 17;
    size_t off = (size_t)(tid & 131071u) * 8;
    const float* s = (arr == 0) ? Wq : (arr == 1) ? Wk : Wv;
    unsigned short* d = (arr == 0) ? oq : (arr == 1) ? ok_ : ov;
    f32x4 a = *reinterpret_cast<const f32x4*>(s + off);
    f32x4 b = *reinterpret_cast<const f32x4*>(s + off + 4);
    short8 r;
#pragma unroll
    for (int j = 0; j < 4; ++j) { r[j] = (short)f2bf(a[j]); r[j + 4] = (short)f2bf(b[j]); }
    *reinterpret_cast<short8*>(d + off) = r;
}

// --------------------------------------------- gemm_bt (Q projection) ----
__global__ __launch_bounds__(256) void gemm_bt(
    const unsigned short* __restrict__ A,
    const unsigned short* __restrict__ W, const float* __restrict__ bias,
    unsigned short* __restrict__ C)
{
    __shared__ __align__(16) unsigned short smem[16384];
    unsigned short* As = smem;
    unsigned short* Bs = smem + 8192;

    int t = threadIdx.x, lane = t & 63, w = t >> 6;
    int wr = w >> 1, wc = w & 1, g = lane >> 4, lr = lane & 15;
    int m0 = blockIdx.x * 128;
    int n0 = blockIdx.y * 128;

    f32x4 acc[4][4];
#pragma unroll
    for (int i = 0; i < 4; ++i)
#pragma unroll
        for (int j = 0; j < 4; ++j) acc[i][j] = (f32x4)0.f;

    int srow = lane >> 3;
    int scb  = (lane & 7) * 16;

    for (int kb = 0; kb < 1024; kb += 64) {
#pragma unroll
        for (int i = 0; i < 4; ++i) {
            int row = i * 32 + w * 8 + srow;
            int cb = scb ^ ((row & 7) << 4);
            const char* ga = (const char*)(A + (size_t)(m0 + row) * 1024 + kb) + cb;
            GLOAD16(ga, &As[(size_t)(i * 32 + w * 8) * 64]);
            const char* gb = (const char*)(W + (size_t)(n0 + row) * 1024 + kb) + cb;
            GLOAD16(gb, &Bs[(size_t)(i * 32 + w * 8) * 64]);
        }
        __syncthreads();
#pragma unroll
        for (int kk = 0; kk < 2; ++kk) {
            int cb0 = kk * 64 + g * 16;
            short8 af[4], bf[4];
#pragma unroll
            for (int mi = 0; mi < 4; ++mi) {
                int row = wr * 64 + mi * 16 + lr;
                af[mi] = *reinterpret_cast<const short8*>(
                    (const char*)As + row * 128 + (cb0 ^ ((row & 7) << 4)));
            }
#pragma unroll
            for (int ni = 0; ni < 4; ++ni) {
                int row = wc * 64 + ni * 16 + lr;
                bf[ni] = *reinterpret_cast<const short8*>(
                    (const char*)Bs + row * 128 + (cb0 ^ ((row & 7) << 4)));
            }
#pragma unroll
            for (int mi = 0; mi < 4; ++mi)
#pragma unroll
                for (int ni = 0; ni < 4; ++ni)
                    acc[mi][ni] = __builtin_amdgcn_mfma_f32_16x16x32_bf16(af[mi], bf[ni], acc[mi][ni], 0, 0, 0);
        }
        __syncthreads();
    }

    unsigned short* Ct = smem;
#pragma unroll
    for (int ni = 0; ni < 4; ++ni) {
        int coll = wc * 64 + ni * 16 + lr;
        float bv = bias[n0 + coll];
#pragma unroll
        for (int mi = 0; mi < 4; ++mi)
#pragma unroll
            for (int j = 0; j < 4; ++j) {
                int rowl = wr * 64 + mi * 16 + g * 4 + j;
                Ct[rowl * 128 + coll] = f2bf(acc[mi][ni][j] + bv);
            }
    }
    __syncthreads();
#pragma unroll
    for (int i = 0; i < 8; ++i) {
        int idx = i * 2048 + t * 8;
        int row = idx >> 7, col = idx & 127;
        *reinterpret_cast<short8*>(C + (size_t)(m0 + row) * 1024 + n0 + col) =
            *reinterpret_cast<const short8*>(&Ct[idx]);
    }
}

// -------------------------------- gemm256: BM=256 BN=128 BK=32, 2 blk/CU ----
// 8 waves (4M x 2N), per-lane acc = 64 VGPR -> fits 128-cap (launch_bounds 4).
// LDS 48KB: A [2][128vr][128B], B [2][64vr][128B]; packed vrow = 2 rows of 64B.
// Slot XOR: global (r, chunk c of 16B) stored at vr=r>>1,
//           sl = ((r&1)*4 + c) ^ (vr&7). gload source uses same involution.
// Phase (x32): {8 ds_read ; 3 gload stage other slot ; barrier ; lgkmcnt(0) ;
//               16 MFMA setprio ; vmcnt(0) ; barrier}  (round-8 proven body)
__global__ __launch_bounds__(512, 4) void gemm256(
    const unsigned short* __restrict__ A, const unsigned short* __restrict__ W,
    const float* __restrict__ b0, const float* __restrict__ b1,
    unsigned short* __restrict__ Cn, unsigned short* __restrict__ Vt,
    int mtiles, int tsplit)
{
    __shared__ __align__(16) char smemc[49152];   // A slots @0,16384; B @32768,40960

    int t = threadIdx.x, lane = t & 63, w = t >> 6, g = lane >> 4, lr = lane & 15;
    int wr = w >> 1, wcn = w & 1;

    int id = blockIdx.x;
    int ntc = gridDim.x / mtiles;              // 16
    int xcd = id & 7, ord = id >> 3;
    int mt = xcd * (mtiles >> 3) + ord / ntc;  // contiguous mt per XCD
    int nt = ord % ntc;                        // nt fastest: A-panel L2 reuse
    int m0 = mt * 256;
    int n0 = nt * 128;

    const char* Ap = (const char*)(A + (size_t)m0 * 1024);
    const char* Wp = (const char*)(W + (size_t)n0 * 1024);

    f32x4 acc[4][4];
#pragma unroll
    for (int i = 0; i < 4; ++i)
#pragma unroll
        for (int j = 0; j < 4; ++j) acc[i][j] = (f32x4)0.f;

    // ---- staging lane constants (vrbase&7 == 0 for all gloads) ----
    int qv = (lane & 7) ^ (lane >> 3);                 // source chunk permutation
    int rA = 2 * (w * 8 + (lane >> 3)) + (qv >> 2);    // global row for gload 0
    size_t offA0 = (size_t)rA * 2048 + (qv & 3) * 16;  // byte offset in panel
    size_t offA1 = offA0 + (size_t)128 * 2048;         // +128 rows
    int ldsA = (w * 8) * 128;                          // wave's vrow base * 128B
    // B uses same lane map (64 vrows total, 1 gload/wave)

    // ---- fragment read offsets (sl independent of mi/ni) ----
    int sl = (((lr & 1) * 4 + g) ^ (lr >> 1)) * 16;
    int afo = (wr * 32 + (lr >> 1)) * 128 + sl;        // + mi*1024
    int bfo = (wcn * 32 + (lr >> 1)) * 128 + sl;       // + ni*1024

    auto STAGE = [&](int slot, int kt) {
        size_t ko = (size_t)kt * 64;
        GLOAD16(Ap + offA0 + ko, smemc + slot * 16384 + ldsA);
        GLOAD16(Ap + offA1 + ko, smemc + slot * 16384 + 8192 + ldsA);
        GLOAD16(Wp + offA0 + ko, smemc + 32768 + slot * 8192 + ldsA);
    };

    // prologue: K-tile 0 -> slot 0
    STAGE(0, 0);
    asm volatile("s_waitcnt vmcnt(0)" ::: "memory");
    __builtin_amdgcn_s_barrier();

    for (int kt = 0; kt < 32; ++kt) {
        const int cs = kt & 1;
        const char* Ab = smemc + cs * 16384;
        const char* Bb = smemc + 32768 + cs * 8192;
        short8 af[4], bfv[4];
#pragma unroll
        for (int mi = 0; mi < 4; ++mi)
            af[mi] = *reinterpret_cast<const short8*>(Ab + afo + mi * 1024);
#pragma unroll
        for (int ni = 0; ni < 4; ++ni)
            bfv[ni] = *reinterpret_cast<const short8*>(Bb + bfo + ni * 1024);
        if (kt < 31) STAGE(cs ^ 1, kt + 1);
        __builtin_amdgcn_sched_barrier(0);
        __builtin_amdgcn_s_barrier();
        asm volatile("s_waitcnt lgkmcnt(0)" ::: "memory");
        __builtin_amdgcn_sched_barrier(0);
        __builtin_amdgcn_s_setprio(1);
#pragma unroll
        for (int mi = 0; mi < 4; ++mi)
#pragma unroll
            for (int ni = 0; ni < 4; ++ni)
                acc[mi][ni] = __builtin_amdgcn_mfma_f32_16x16x32_bf16(af[mi], bfv[ni], acc[mi][ni], 0, 0, 0);
        __builtin_amdgcn_s_setprio(0);
        asm volatile("s_waitcnt vmcnt(0)" ::: "memory");
        __builtin_amdgcn_sched_barrier(0);
        __builtin_amdgcn_s_barrier();
    }
    __syncthreads();

    unsigned short* CtS = (unsigned short*)smemc;
    if (nt < tsplit) {
        // normal: 4 chunks of 64 rows x 128 cols, CtS [64][136]
#pragma unroll
        for (int ch = 0; ch < 4; ++ch) {
            if (ch) __syncthreads();
            if (wr == ch) {
#pragma unroll
                for (int ni = 0; ni < 4; ++ni) {
                    int c = wcn * 64 + ni * 16 + lr;
                    float bvv = b0[n0 + c];
#pragma unroll
                    for (int mi = 0; mi < 4; ++mi)
#pragma unroll
                        for (int j = 0; j < 4; ++j)
                            CtS[(mi * 16 + g * 4 + j) * 136 + c] = f2bf(acc[mi][ni][j] + bvv);
                }
            }
            __syncthreads();
#pragma unroll
            for (int it = 0; it < 2; ++it) {
                int u2 = it * 512 + t;
                int row = u2 >> 4, c8 = u2 & 15;
                *reinterpret_cast<short8*>(Cn + (size_t)(m0 + ch * 64 + row) * 1024 + n0 + c8 * 8) =
                    *reinterpret_cast<const short8*>(&CtS[row * 136 + c8 * 8]);
            }
        }
    } else {
        // transposed: 2 chunks of 64 d-rows x 256 kv, CtS [64][272]
        int h = nt - tsplit;
        int b = m0 >> 12, kv0 = m0 & 4095;
#pragma unroll
        for (int ch = 0; ch < 2; ++ch) {
            if (ch) __syncthreads();
            if (wcn == ch) {
#pragma unroll
                for (int ni = 0; ni < 4; ++ni) {
                    int dl = ni * 16 + lr;                       // 0..63
                    float bvv = b1[h * 128 + ch * 64 + dl];
#pragma unroll
                    for (int mi = 0; mi < 4; ++mi)
#pragma unroll
                        for (int j = 0; j < 4; ++j)
                            CtS[dl * 272 + wr * 64 + mi * 16 + g * 4 + j] = f2bf(acc[mi][ni][j] + bvv);
                }
            }
            __syncthreads();
            unsigned short* dst = Vt + ((size_t)(b * 8 + h) * 128 + ch * 64) * 4096 + kv0;
#pragma unroll
            for (int it = 0; it < 4; ++it) {
                int u2 = it * 512 + t;
                int row = u2 >> 5, c8 = u2 & 31;
                *reinterpret_cast<short8*>(dst + (size_t)row * 4096 + c8 * 8) =
                    *reinterpret_cast<const short8*>(&CtS[row * 272 + c8 * 8]);
            }
        }
    }
}

// ----------------------------------------------------------- attention ----
// unchanged (verified): swapped QK^T, defer-max, packed P, dbuf gload_lds.
__global__ __launch_bounds__(256, 2) void attn_kernel(
    const unsigned short* __restrict__ Qm, const unsigned short* __restrict__ Km,
    const unsigned short* __restrict__ VtG, const float* __restrict__ hidden,
    float* __restrict__ out)
{
    __shared__ __align__(16) unsigned short Kl[2][64 * 128];
    __shared__ __align__(16) unsigned short Vt[2][128 * 64];
    __shared__ __align__(16) unsigned short Pl[64 * 64];

    int t = threadIdx.x, lane = t & 63, w = t >> 6, g = lane >> 4, lr = lane & 15;
    int id = blockIdx.x;
    int swz = (id & 7) * 64 + (id >> 3);
    int qt = swz & 7, h = (swz >> 3) & 7, b = swz >> 6;

    short8 qf[4];
#pragma unroll
    for (int kk = 0; kk < 4; ++kk)
        qf[kk] = *reinterpret_cast<const short8*>(
            Qm + (size_t)(b * 512 + qt * 64 + w * 16 + lr) * 1024 + h * 128 + kk * 32 + g * 8);
    asm volatile("s_waitcnt vmcnt(0)" ::: "memory");

    float m2 = 0.f;
    float l = 0.f;
    f32x4 oacc[8];
#pragma unroll
    for (int nf = 0; nf < 8; ++nf) oacc[nf] = (f32x4)0.f;

    const float SCALE = 0.08838834764831845f;
    const float LOG2E = 1.4426950408889634f;
    const float K1 = SCALE * LOG2E;
    const float THR2 = 11.5f;

    size_t kbase = (size_t)b * 4096 * 1024 + h * 128;
    size_t vbase = ((size_t)(b * 8 + h)) * 128 * 4096;

    auto STAGE_K = [&](int buf, int c) {
        int kv0 = c * 64;
#pragma unroll
        for (int i = 0; i < 4; ++i) {
            int rb = w * 16 + i * 4;
            int row = rb + (lane >> 4);
            int cb = ((lane & 15) * 16) ^ ((row & 7) << 4);
            const char* gp = (const char*)(Km + kbase + (size_t)(kv0 + row) * 1024) + cb;
            GLOAD16(gp, &Kl[buf][rb * 128]);
        }
    };
    auto STAGE_V = [&](int buf, int c) {
        int kv0 = c * 64;
#pragma unroll
        for (int i = 0; i < 4; ++i) {
            int db = w * 32 + i * 8;
            int d = db + (lane >> 3);
            int cb = ((lane & 7) * 16) ^ ((d & 7) << 4);
            const char* gp = (const char*)(VtG + vbase + (size_t)d * 4096 + kv0) + cb;
            GLOAD16(gp, &Vt[buf][db * 64]);
        }
    };

    STAGE_K(0, 0); STAGE_V(0, 0);

    for (int c = 0; c < 64; ++c) {
        int cur = c & 1;
        asm volatile("s_waitcnt vmcnt(0) lgkmcnt(0)" ::: "memory");
        __builtin_amdgcn_sched_barrier(0);
        __builtin_amdgcn_s_barrier();
        if (c < 63) { STAGE_K(cur ^ 1, c + 1); STAGE_V(cur ^ 1, c + 1); }

        f32x4 sacc[4];
#pragma unroll
        for (int nf = 0; nf < 4; ++nf) sacc[nf] = (f32x4)0.f;
#pragma unroll
        for (int kk = 0; kk < 4; ++kk) {
            int cb0 = kk * 64 + g * 16;
            short8 kf[4];
#pragma unroll
            for (int nf = 0; nf < 4; ++nf) {
                int row = nf * 16 + lr;
                kf[nf] = *reinterpret_cast<const short8*>(
                    (const char*)&Kl[cur][0] + row * 256 + (cb0 ^ ((row & 7) << 4)));
            }
            __builtin_amdgcn_s_setprio(1);
#pragma unroll
            for (int nf = 0; nf < 4; ++nf)
                sacc[nf] = __builtin_amdgcn_mfma_f32_16x16x32_bf16(kf[nf], qf[kk], sacc[nf], 0, 0, 0);
            __builtin_amdgcn_s_setprio(0);
        }

        float smax = sacc[0][0];
#pragma unroll
        for (int nf = 0; nf < 4; ++nf)
#pragma unroll
            for (int j = 0; j < 4; ++j) smax = fmaxf(smax, sacc[nf][j]);
        float s2max = smax * K1;
        if (!__all(s2max <= m2 + THR2)) {
            float rm = s2max;
            rm = fmaxf(rm, __shfl_xor(rm, 16));
            rm = fmaxf(rm, __shfl_xor(rm, 32));
            float m2n = fmaxf(m2, rm);
            float corr = exp2f(m2 - m2n);
            l *= corr;
            m2 = m2n;
#pragma unroll
            for (int j = 0; j < 4; ++j) {
                float cj = __shfl(corr, g * 4 + j);
#pragma unroll
                for (int nf = 0; nf < 8; ++nf) oacc[nf][j] *= cj;
            }
        }
        int prow = w * 16 + lr;
        int rsw = (lr & 7) << 4;
#pragma unroll
        for (int nf = 0; nf < 4; ++nf) {
            float p0 = exp2f(sacc[nf][0] * K1 - m2);
            float p1 = exp2f(sacc[nf][1] * K1 - m2);
            float p2 = exp2f(sacc[nf][2] * K1 - m2);
            float p3 = exp2f(sacc[nf][3] * K1 - m2);
            l += (p0 + p1) + (p2 + p3);
            bf16x4 pk;
            pk[0] = (short)f2bf(p0); pk[1] = (short)f2bf(p1);
            pk[2] = (short)f2bf(p2); pk[3] = (short)f2bf(p3);
            *reinterpret_cast<bf16x4*>(
                (char*)Pl + prow * 128 + ((nf * 32 + g * 8) ^ rsw)) = pk;
        }
        asm volatile("s_waitcnt lgkmcnt(0)" ::: "memory");
        __builtin_amdgcn_sched_barrier(0);

#pragma unroll
        for (int kp = 0; kp < 2; ++kp) {
            int cb0 = kp * 64 + g * 16;
            short8 pa = *reinterpret_cast<const short8*>(
                (const char*)Pl + prow * 128 + (cb0 ^ rsw));
#pragma unroll
            for (int nf = 0; nf < 8; ++nf) {
                int d = nf * 16 + lr;
                short8 vb = *reinterpret_cast<const short8*>(
                    (const char*)&Vt[cur][0] + d * 128 + (cb0 ^ ((d & 7) << 4)));
                oacc[nf] = __builtin_amdgcn_mfma_f32_16x16x32_bf16(pa, vb, oacc[nf], 0, 0, 0);
            }
        }
    }

    l += __shfl_xor(l, 16);
    l += __shfl_xor(l, 32);
#pragma unroll
    for (int j = 0; j < 4; ++j) {
        float lj = __shfl(l, g * 4 + j);
        float inv = 1.f / lj;
        int q = qt * 64 + w * 16 + g * 4 + j;
        size_t base = (size_t)(b * 512 + q) * 1024 + h * 128;
#pragma unroll
        for (int nf = 0; nf < 8; ++nf) {
            int d = nf * 16 + lr;
            out[base + d] = hidden[base + d] + oacc[nf][j] * inv;
        }
    }
}

// ---------------------------------------------------------------- host ----
extern "C" void kernel_launch(void* const* d_in, const int* in_sizes, int n_in,
                              void* d_out, int out_size, void* d_ws, size_t ws_size,
                              hipStream_t stream) {
    const float* hidden = (const float*)d_in[0];
    const float* inputs = (const float*)d_in[1];
    const float* ln1w   = (const float*)d_in[2];
    const float* ln1b   = (const float*)d_in[3];
    const float* ln2w   = (const float*)d_in[4];
    const float* ln2b   = (const float*)d_in[5];
    const float* Wq     = (const float*)d_in[6];
    const float* bq     = (const float*)d_in[7];
    const float* Wk     = (const float*)d_in[8];
    const float* bk     = (const float*)d_in[9];
    const float* Wv     = (const float*)d_in[10];
    const float* bv     = (const float*)d_in[11];
    float* out = (float*)d_out;
    char* ws = (char*)d_ws;

    unsigned short* LNh = (unsigned short*)ws;        // 4096x1024 bf16
    unsigned short* LNx = LNh + 4194304;              // 32768x1024
    unsigned short* WqB = LNx + 33554432;             // Wq, then Wk|Wv contiguous
    unsigned short* WkB = WqB + 1048576;
    unsigned short* WvB = WkB + 1048576;
    unsigned short* Qm  = WvB + 1048576;              // 4096x1024
    unsigned short* Km  = Qm + 4194304;               // 32768x1024
    unsigned short* VtG = Km + 33554432;              // [b][h][128 d][4096 kv]

    ln_bf16<<<dim3(9216), dim3(256), 0, stream>>>(hidden, inputs, ln1w, ln1b, ln2w, ln2b, LNh, LNx);
    convert_w<<<dim3(1536), dim3(256), 0, stream>>>(Wq, Wk, Wv, WqB, WkB, WvB);
    gemm_bt<<<dim3(32, 8), dim3(256), 0, stream>>>(LNh, WqB, bq, Qm);
    // K|V: M=32768 (128 mtiles x 256), N=2048 (16 ntiles x 128); nt>=8 -> V transposed
    gemm256<<<dim3(2048), dim3(512), 0, stream>>>(LNx, WkB, bk, bv, Km, VtG, 128, 8);
    attn_kernel<<<dim3(512), dim3(256), 0, stream>>>(Qm, Km, VtG, hidden, out);
}

// Round 12
// 330.734 us; speedup vs baseline: 3.7134x; 1.0586x over previous
//
#include <hip/hip_runtime.h>

typedef __attribute__((ext_vector_type(8))) short short8;
typedef __attribute__((ext_vector_type(4))) short bf16x4;
typedef __attribute__((ext_vector_type(4))) float f32x4;

#define DEV __device__ __forceinline__

DEV unsigned short f2bf(float f) {
    unsigned int u = __builtin_bit_cast(unsigned int, f);
    u += 0x7fffu + ((u >> 16) & 1u);
    return (unsigned short)(u >> 16);
}

#define GLOAD16(gp, lp)                                                        \
    __builtin_amdgcn_global_load_lds(                                          \
        (const __attribute__((address_space(1))) void*)(gp),                   \
        (__attribute__((address_space(3))) void*)(lp), 16, 0, 0)

// ---------------------------------------------------- prep (LN + convert) ----
// blocks [0,9216): LayerNorm rows (4 rows/block); [9216,10752): weight fp32->bf16.
__global__ __launch_bounds__(256) void prep(
    const float* __restrict__ hidden, const float* __restrict__ inputs,
    const float* __restrict__ ln1w, const float* __restrict__ ln1b,
    const float* __restrict__ ln2w, const float* __restrict__ ln2b,
    const float* __restrict__ Wq, const float* __restrict__ Wk, const float* __restrict__ Wv,
    unsigned short* __restrict__ LNh, unsigned short* __restrict__ LNx,
    unsigned short* __restrict__ WqB, unsigned short* __restrict__ WkB, unsigned short* __restrict__ WvB)
{
    if (blockIdx.x < 9216) {
        int row = blockIdx.x * 4 + (threadIdx.x >> 6);
        int lane = threadIdx.x & 63;
        const float *src, *wp, *bp; unsigned short* dst;
        if (row < 4096) { src = hidden + (size_t)row * 1024; wp = ln1w; bp = ln1b; dst = LNh + (size_t)row * 1024; }
        else { int r = row - 4096; src = inputs + (size_t)r * 1024; wp = ln2w; bp = ln2b; dst = LNx + (size_t)r * 1024; }

        f32x4 v[4];
        float s = 0.f, ss = 0.f;
#pragma unroll
        for (int i = 0; i < 4; ++i) {
            v[i] = *reinterpret_cast<const f32x4*>(src + i * 256 + lane * 4);
#pragma unroll
            for (int j = 0; j < 4; ++j) { s += v[i][j]; ss += v[i][j] * v[i][j]; }
        }
#pragma unroll
        for (int off = 32; off >= 1; off >>= 1) { s += __shfl_xor(s, off); ss += __shfl_xor(ss, off); }
        float mu = s * (1.f / 1024.f);
        float var = fmaxf(ss * (1.f / 1024.f) - mu * mu, 0.f);
        float rs = rsqrtf(var + 1e-5f);
#pragma unroll
        for (int i = 0; i < 4; ++i) {
            f32x4 wv = *reinterpret_cast<const f32x4*>(wp + i * 256 + lane * 4);
            f32x4 bv = *reinterpret_cast<const f32x4*>(bp + i * 256 + lane * 4);
            bf16x4 o;
#pragma unroll
            for (int j = 0; j < 4; ++j) o[j] = (short)f2bf((v[i][j] - mu) * rs * wv[j] + bv[j]);
            *reinterpret_cast<bf16x4*>(dst + i * 256 + lane * 4) = o;
        }
    } else {
        unsigned tid = (blockIdx.x - 9216) * 256 + threadIdx.x;
        int arr = tid >> 17;
        size_t off = (size_t)(tid & 131071u) * 8;
        const float* s = (arr == 0) ? Wq : (arr == 1) ? Wk : Wv;
        unsigned short* d = (arr == 0) ? WqB : (arr == 1) ? WkB : WvB;
        f32x4 a = *reinterpret_cast<const f32x4*>(s + off);
        f32x4 b = *reinterpret_cast<const f32x4*>(s + off + 4);
        short8 r;
#pragma unroll
        for (int j = 0; j < 4; ++j) { r[j] = (short)f2bf(a[j]); r[j + 4] = (short)f2bf(b[j]); }
        *reinterpret_cast<short8*>(d + off) = r;
    }
}

// ------------------------------------------- gemm256 (round-8 body, merged) ----
// blocks [0,1024): K|V projections (A=LNx, W=WkB|WvB, nt>=4 -> V transposed).
// blocks [1024,1088): Q projection (A=LNh, W=WqB, normal epilogue to Qm).
// Per phase: {8 ds_read ; stage 2 gload_lds ; barrier ; lgkmcnt(0) ; 16 MFMA ;
//             [p==3|7: vmcnt(0)] ; barrier}  — verified round-8 schedule.
__global__ __launch_bounds__(512, 2) void gemm256(
    const unsigned short* __restrict__ A, const unsigned short* __restrict__ Ah,
    const unsigned short* __restrict__ W, const unsigned short* __restrict__ Wqb,
    const float* __restrict__ bk, const float* __restrict__ bv, const float* __restrict__ bq,
    unsigned short* __restrict__ Cn, unsigned short* __restrict__ Vt, unsigned short* __restrict__ Qm)
{
    __shared__ __align__(16) char smemc[131072];

    int t = threadIdx.x, lane = t & 63, w = t >> 6, g = lane >> 4, lr = lane & 15;
    int wr = w >> 2, wcn = w & 3;
    int R0 = wr * 128, C0 = wcn * 64;

    int id = blockIdx.x;
    int m0, n0, trans = 0;
    const unsigned short *Ab_, *Wb_;
    const float* bias;
    unsigned short* Cout;
    if (id < 1024) {
        int xcd = id & 7, ord = id >> 3;
        int mt = xcd * 16 + ord / 8;          // contiguous mt chunk per XCD
        int nt = ord % 8;                     // nt fastest: A-panel L2 reuse
        m0 = mt * 256; n0 = nt * 256;
        Ab_ = A; Wb_ = W;
        if (nt < 4) { bias = bk; Cout = Cn; }
        else        { bias = bv; Cout = Vt; trans = 1; }
    } else {
        int id2 = id - 1024;
        int mt = id2 & 15, nt = id2 >> 4;     // Q: M=4096 (16 mt), N=1024 (4 nt)
        m0 = mt * 256; n0 = nt * 256;
        Ab_ = Ah; Wb_ = Wqb;
        bias = bq; Cout = Qm;
    }

    const unsigned short* Ap = Ab_ + (size_t)m0 * 1024;
    const unsigned short* Wp = Wb_ + (size_t)n0 * 1024;

    f32x4 acc[8][4];
#pragma unroll
    for (int i = 0; i < 8; ++i)
#pragma unroll
        for (int j = 0; j < 4; ++j) acc[i][j] = (f32x4)0.f;

    auto STAGE = [&](int slot, int kt, int sel) {
        const unsigned short* P = (sel < 2) ? Ap : Wp;
        char* ldsb = smemc + ((sel < 2) ? 0 : 65536) + slot * 32768;
        int h = sel & 1;
#pragma unroll
        for (int i = 0; i < 2; ++i) {
            int rtb = h * 128 + i * 64 + w * 8;
            int rt = rtb + (lane >> 3);
            int sc = ((lane & 7) * 16) ^ ((rt & 7) << 4);
            const char* gp = (const char*)(P + (size_t)rt * 1024 + kt * 64) + sc;
            GLOAD16(gp, ldsb + rtb * 128);
        }
    };

    // prologue: K-tile 0 -> slot 0, verified before any reads
    STAGE(0, 0, 0); STAGE(0, 0, 1); STAGE(0, 0, 2); STAGE(0, 0, 3);
    asm volatile("s_waitcnt vmcnt(0)" ::: "memory");
    __builtin_amdgcn_s_barrier();

    for (int u = 0; u < 8; ++u) {
#pragma unroll
        for (int p = 0; p < 8; ++p) {
            const int cs = p >> 2, mq = p & 1, ks = (p >> 1) & 1;
            const char* Abp = smemc + cs * 32768;
            const char* Bbp = smemc + 65536 + cs * 32768;
            int cb0 = ks * 64 + g * 16;
            short8 af[4], bfv[4];
#pragma unroll
            for (int a = 0; a < 4; ++a) {
                int r = R0 + (mq * 4 + a) * 16 + lr;
                af[a] = *reinterpret_cast<const short8*>(Abp + r * 128 + (cb0 ^ ((r & 7) << 4)));
            }
#pragma unroll
            for (int ni = 0; ni < 4; ++ni) {
                int r = C0 + ni * 16 + lr;
                bfv[ni] = *reinterpret_cast<const short8*>(Bbp + r * 128 + (cb0 ^ ((r & 7) << 4)));
            }
            if (p < 4)      STAGE(1, 2 * u + 1, p);
            else if (u < 7) STAGE(0, 2 * u + 2, p - 4);
            __builtin_amdgcn_sched_barrier(0);
            __builtin_amdgcn_s_barrier();
            asm volatile("s_waitcnt lgkmcnt(0)" ::: "memory");
            __builtin_amdgcn_sched_barrier(0);
            __builtin_amdgcn_s_setprio(1);
#pragma unroll
            for (int a = 0; a < 4; ++a)
#pragma unroll
                for (int ni = 0; ni < 4; ++ni)
                    acc[mq * 4 + a][ni] =
                        __builtin_amdgcn_mfma_f32_16x16x32_bf16(af[a], bfv[ni], acc[mq * 4 + a][ni], 0, 0, 0);
            __builtin_amdgcn_s_setprio(0);
            if (p == 3 || p == 7) asm volatile("s_waitcnt vmcnt(0)" ::: "memory");
            __builtin_amdgcn_sched_barrier(0);
            __builtin_amdgcn_s_barrier();
        }
    }
    __syncthreads();

    unsigned short* CtS = (unsigned short*)smemc;
    if (!trans) {
#pragma unroll
        for (int mh = 0; mh < 2; ++mh) {
            if (mh) __syncthreads();
            if (wr == mh) {
#pragma unroll
                for (int ni = 0; ni < 4; ++ni) {
                    int c = C0 + ni * 16 + lr;
                    float bvv = bias[n0 + c];
#pragma unroll
                    for (int mi = 0; mi < 8; ++mi)
#pragma unroll
                        for (int j = 0; j < 4; ++j)
                            CtS[(mi * 16 + g * 4 + j) * 272 + c] = f2bf(acc[mi][ni][j] + bvv);
                }
            }
            __syncthreads();
#pragma unroll
            for (int it = 0; it < 8; ++it) {
                int u2 = it * 512 + t;
                int row = u2 >> 5, c16 = u2 & 31;
                *reinterpret_cast<short8*>(Cout + (size_t)(m0 + mh * 128 + row) * 1024 + n0 + c16 * 8) =
                    *reinterpret_cast<const short8*>(&CtS[row * 272 + c16 * 8]);
            }
        }
    } else {
        int nt = n0 >> 8;                      // 4..7
        int hbase = (nt - 4) * 2;
        int b = m0 >> 12, kv0 = m0 & 4095;
#pragma unroll
        for (int ch = 0; ch < 2; ++ch) {
            if (ch) __syncthreads();
            if ((wcn >> 1) == ch) {
#pragma unroll
                for (int ni = 0; ni < 4; ++ni) {
                    int rowc = (wcn & 1) * 64 + ni * 16 + lr;
                    float bvv = bias[n0 - 1024 + ch * 128 + rowc];
#pragma unroll
                    for (int mi = 0; mi < 8; ++mi)
#pragma unroll
                        for (int j = 0; j < 4; ++j)
                            CtS[rowc * 272 + wr * 128 + mi * 16 + g * 4 + j] = f2bf(acc[mi][ni][j] + bvv);
                }
            }
            __syncthreads();
            unsigned short* dst = Cout + ((size_t)(b * 8 + hbase + ch) * 128) * 4096 + kv0;
#pragma unroll
            for (int it = 0; it < 8; ++it) {
                int u2 = it * 512 + t;
                int row = u2 >> 5, c16 = u2 & 31;
                *reinterpret_cast<short8*>(dst + (size_t)row * 4096 + c16 * 8) =
                    *reinterpret_cast<const short8*>(&CtS[row * 272 + c16 * 8]);
            }
        }
    }
}

// ----------------------------------------------------------- attention ----
// unchanged (verified): swapped QK^T, defer-max, packed P, dbuf gload_lds.
__global__ __launch_bounds__(256, 2) void attn_kernel(
    const unsigned short* __restrict__ Qm, const unsigned short* __restrict__ Km,
    const unsigned short* __restrict__ VtG, const float* __restrict__ hidden,
    float* __restrict__ out)
{
    __shared__ __align__(16) unsigned short Kl[2][64 * 128];
    __shared__ __align__(16) unsigned short Vt[2][128 * 64];
    __shared__ __align__(16) unsigned short Pl[64 * 64];

    int t = threadIdx.x, lane = t & 63, w = t >> 6, g = lane >> 4, lr = lane & 15;
    int id = blockIdx.x;
    int swz = (id & 7) * 64 + (id >> 3);
    int qt = swz & 7, h = (swz >> 3) & 7, b = swz >> 6;

    short8 qf[4];
#pragma unroll
    for (int kk = 0; kk < 4; ++kk)
        qf[kk] = *reinterpret_cast<const short8*>(
            Qm + (size_t)(b * 512 + qt * 64 + w * 16 + lr) * 1024 + h * 128 + kk * 32 + g * 8);
    asm volatile("s_waitcnt vmcnt(0)" ::: "memory");

    float m2 = 0.f;
    float l = 0.f;
    f32x4 oacc[8];
#pragma unroll
    for (int nf = 0; nf < 8; ++nf) oacc[nf] = (f32x4)0.f;

    const float SCALE = 0.08838834764831845f;
    const float LOG2E = 1.4426950408889634f;
    const float K1 = SCALE * LOG2E;
    const float THR2 = 11.5f;

    size_t kbase = (size_t)b * 4096 * 1024 + h * 128;
    size_t vbase = ((size_t)(b * 8 + h)) * 128 * 4096;

    auto STAGE_K = [&](int buf, int c) {
        int kv0 = c * 64;
#pragma unroll
        for (int i = 0; i < 4; ++i) {
            int rb = w * 16 + i * 4;
            int row = rb + (lane >> 4);
            int cb = ((lane & 15) * 16) ^ ((row & 7) << 4);
            const char* gp = (const char*)(Km + kbase + (size_t)(kv0 + row) * 1024) + cb;
            GLOAD16(gp, &Kl[buf][rb * 128]);
        }
    };
    auto STAGE_V = [&](int buf, int c) {
        int kv0 = c * 64;
#pragma unroll
        for (int i = 0; i < 4; ++i) {
            int db = w * 32 + i * 8;
            int d = db + (lane >> 3);
            int cb = ((lane & 7) * 16) ^ ((d & 7) << 4);
            const char* gp = (const char*)(VtG + vbase + (size_t)d * 4096 + kv0) + cb;
            GLOAD16(gp, &Vt[buf][db * 64]);
        }
    };

    STAGE_K(0, 0); STAGE_V(0, 0);

    for (int c = 0; c < 64; ++c) {
        int cur = c & 1;
        asm volatile("s_waitcnt vmcnt(0) lgkmcnt(0)" ::: "memory");
        __builtin_amdgcn_sched_barrier(0);
        __builtin_amdgcn_s_barrier();
        if (c < 63) { STAGE_K(cur ^ 1, c + 1); STAGE_V(cur ^ 1, c + 1); }

        f32x4 sacc[4];
#pragma unroll
        for (int nf = 0; nf < 4; ++nf) sacc[nf] = (f32x4)0.f;
#pragma unroll
        for (int kk = 0; kk < 4; ++kk) {
            int cb0 = kk * 64 + g * 16;
            short8 kf[4];
#pragma unroll
            for (int nf = 0; nf < 4; ++nf) {
                int row = nf * 16 + lr;
                kf[nf] = *reinterpret_cast<const short8*>(
                    (const char*)&Kl[cur][0] + row * 256 + (cb0 ^ ((row & 7) << 4)));
            }
            __builtin_amdgcn_s_setprio(1);
#pragma unroll
            for (int nf = 0; nf < 4; ++nf)
                sacc[nf] = __builtin_amdgcn_mfma_f32_16x16x32_bf16(kf[nf], qf[kk], sacc[nf], 0, 0, 0);
            __builtin_amdgcn_s_setprio(0);
        }

        float smax = sacc[0][0];
#pragma unroll
        for (int nf = 0; nf < 4; ++nf)
#pragma unroll
            for (int j = 0; j < 4; ++j) smax = fmaxf(smax, sacc[nf][j]);
        float s2max = smax * K1;
        if (!__all(s2max <= m2 + THR2)) {
            float rm = s2max;
            rm = fmaxf(rm, __shfl_xor(rm, 16));
            rm = fmaxf(rm, __shfl_xor(rm, 32));
            float m2n = fmaxf(m2, rm);
            float corr = exp2f(m2 - m2n);
            l *= corr;
            m2 = m2n;
#pragma unroll
            for (int j = 0; j < 4; ++j) {
                float cj = __shfl(corr, g * 4 + j);
#pragma unroll
                for (int nf = 0; nf < 8; ++nf) oacc[nf][j] *= cj;
            }
        }
        int prow = w * 16 + lr;
        int rsw = (lr & 7) << 4;
#pragma unroll
        for (int nf = 0; nf < 4; ++nf) {
            float p0 = exp2f(sacc[nf][0] * K1 - m2);
            float p1 = exp2f(sacc[nf][1] * K1 - m2);
            float p2 = exp2f(sacc[nf][2] * K1 - m2);
            float p3 = exp2f(sacc[nf][3] * K1 - m2);
            l += (p0 + p1) + (p2 + p3);
            bf16x4 pk;
            pk[0] = (short)f2bf(p0); pk[1] = (short)f2bf(p1);
            pk[2] = (short)f2bf(p2); pk[3] = (short)f2bf(p3);
            *reinterpret_cast<bf16x4*>(
                (char*)Pl + prow * 128 + ((nf * 32 + g * 8) ^ rsw)) = pk;
        }
        asm volatile("s_waitcnt lgkmcnt(0)" ::: "memory");
        __builtin_amdgcn_sched_barrier(0);

#pragma unroll
        for (int kp = 0; kp < 2; ++kp) {
            int cb0 = kp * 64 + g * 16;
            short8 pa = *reinterpret_cast<const short8*>(
                (const char*)Pl + prow * 128 + (cb0 ^ rsw));
#pragma unroll
            for (int nf = 0; nf < 8; ++nf) {
                int d = nf * 16 + lr;
                short8 vb = *reinterpret_cast<const short8*>(
                    (const char*)&Vt[cur][0] + d * 128 + (cb0 ^ ((d & 7) << 4)));
                oacc[nf] = __builtin_amdgcn_mfma_f32_16x16x32_bf16(pa, vb, oacc[nf], 0, 0, 0);
            }
        }
    }

    l += __shfl_xor(l, 16);
    l += __shfl_xor(l, 32);
#pragma unroll
    for (int j = 0; j < 4; ++j) {
        float lj = __shfl(l, g * 4 + j);
        float inv = 1.f / lj;
        int q = qt * 64 + w * 16 + g * 4 + j;
        size_t base = (size_t)(b * 512 + q) * 1024 + h * 128;
#pragma unroll
        for (int nf = 0; nf < 8; ++nf) {
            int d = nf * 16 + lr;
            out[base + d] = hidden[base + d] + oacc[nf][j] * inv;
        }
    }
}

// ---------------------------------------------------------------- host ----
extern "C" void kernel_launch(void* const* d_in, const int* in_sizes, int n_in,
                              void* d_out, int out_size, void* d_ws, size_t ws_size,
                              hipStream_t stream) {
    const float* hidden = (const float*)d_in[0];
    const float* inputs = (const float*)d_in[1];
    const float* ln1w   = (const float*)d_in[2];
    const float* ln1b   = (const float*)d_in[3];
    const float* ln2w   = (const float*)d_in[4];
    const float* ln2b   = (const float*)d_in[5];
    const float* Wq     = (const float*)d_in[6];
    const float* bq     = (const float*)d_in[7];
    const float* Wk     = (const float*)d_in[8];
    const float* bk     = (const float*)d_in[9];
    const float* Wv     = (const float*)d_in[10];
    const float* bv     = (const float*)d_in[11];
    float* out = (float*)d_out;
    char* ws = (char*)d_ws;

    unsigned short* LNh = (unsigned short*)ws;        // 4096x1024 bf16
    unsigned short* LNx = LNh + 4194304;              // 32768x1024
    unsigned short* WqB = LNx + 33554432;             // Wq, then Wk|Wv contiguous
    unsigned short* WkB = WqB + 1048576;
    unsigned short* WvB = WkB + 1048576;
    unsigned short* Qm  = WvB + 1048576;              // 4096x1024
    unsigned short* Km  = Qm + 4194304;               // 32768x1024
    unsigned short* VtG = Km + 33554432;              // [b][h][128 d][4096 kv]

    prep<<<dim3(10752), dim3(256), 0, stream>>>(
        hidden, inputs, ln1w, ln1b, ln2w, ln2b, Wq, Wk, Wv, LNh, LNx, WqB, WkB, WvB);
    gemm256<<<dim3(1088), dim3(512), 0, stream>>>(
        LNx, LNh, WkB, WqB, bk, bv, bq, Km, VtG, Qm);
    attn_kernel<<<dim3(512), dim3(256), 0, stream>>>(Qm, Km, VtG, hidden, out);
}

// Round 13
// 311.721 us; speedup vs baseline: 3.9399x; 1.0610x over previous
//
#include <hip/hip_runtime.h>
#include <hip/hip_fp8.h>

typedef __attribute__((ext_vector_type(8))) short short8;
typedef __attribute__((ext_vector_type(4))) short bf16x4;
typedef __attribute__((ext_vector_type(4))) float f32x4;
typedef __attribute__((ext_vector_type(2))) long i64x2;

#define DEV __device__ __forceinline__

DEV unsigned short f2bf(float f) {
    unsigned int u = __builtin_bit_cast(unsigned int, f);
    u += 0x7fffu + ((u >> 16) & 1u);
    return (unsigned short)(u >> 16);
}

DEV unsigned char f2fp8(float f) {
    return __hip_fp8_e4m3(f).__x;
}

#define GLOAD16(gp, lp)                                                        \
    __builtin_amdgcn_global_load_lds(                                          \
        (const __attribute__((address_space(1))) void*)(gp),                   \
        (__attribute__((address_space(3))) void*)(lp), 16, 0, 0)

// ---------------------------------------------------- prep (LN+convert, fp8) ----
// K-permutation pi per 64-block: stored[16j+i] = logical[8j+i],
// stored[16j+8+i] = logical[32+8j+i]  (i<8, j<4). Applied to BOTH activations
// and weights -> dot products unchanged, but ds_read_b128 at byte g*16 yields
// a lane's (ks0, ks1) fp8 fragments directly.
// blocks [0,9216): LN rows (4/block, 1 wave/row, lane = 16 contiguous k).
// blocks [9216,9984): weights fp32 -> fp8 (x64 scale).
__global__ __launch_bounds__(256) void prep(
    const float* __restrict__ hidden, const float* __restrict__ inputs,
    const float* __restrict__ ln1w, const float* __restrict__ ln1b,
    const float* __restrict__ ln2w, const float* __restrict__ ln2b,
    const float* __restrict__ Wq, const float* __restrict__ Wk, const float* __restrict__ Wv,
    unsigned char* __restrict__ LNh8, unsigned char* __restrict__ LNx8,
    unsigned char* __restrict__ Wq8, unsigned char* __restrict__ Wk8, unsigned char* __restrict__ Wv8)
{
    if (blockIdx.x < 9216) {
        int row = blockIdx.x * 4 + (threadIdx.x >> 6);
        int lane = threadIdx.x & 63;
        const float *src, *wp, *bp; unsigned char* dst;
        if (row < 4096) { src = hidden + (size_t)row * 1024; wp = ln1w; bp = ln1b; dst = LNh8 + (size_t)row * 1024; }
        else { int r = row - 4096; src = inputs + (size_t)r * 1024; wp = ln2w; bp = ln2b; dst = LNx8 + (size_t)r * 1024; }

        f32x4 v[4];
        float s = 0.f, ss = 0.f;
#pragma unroll
        for (int i = 0; i < 4; ++i) {
            v[i] = *reinterpret_cast<const f32x4*>(src + lane * 16 + i * 4);
#pragma unroll
            for (int j = 0; j < 4; ++j) { s += v[i][j]; ss += v[i][j] * v[i][j]; }
        }
#pragma unroll
        for (int off = 32; off >= 1; off >>= 1) { s += __shfl_xor(s, off); ss += __shfl_xor(ss, off); }
        float mu = s * (1.f / 1024.f);
        float var = fmaxf(ss * (1.f / 1024.f) - mu * mu, 0.f);
        float rs = rsqrtf(var + 1e-5f);

        unsigned char by[16];
#pragma unroll
        for (int i = 0; i < 4; ++i) {
            f32x4 wv = *reinterpret_cast<const f32x4*>(wp + lane * 16 + i * 4);
            f32x4 bv = *reinterpret_cast<const f32x4*>(bp + lane * 16 + i * 4);
#pragma unroll
            for (int j = 0; j < 4; ++j)
                by[i * 4 + j] = f2fp8((v[i][j] - mu) * rs * wv[j] + bv[j]);
        }
        int o = (lane * 16) & 63;
        int s0 = (o < 32) ? 2 * o : 2 * (o - 32) + 8;
        unsigned char* base = dst + (lane >> 2) * 64;
        *reinterpret_cast<unsigned long long*>(base + s0)      = *reinterpret_cast<unsigned long long*>(&by[0]);
        *reinterpret_cast<unsigned long long*>(base + s0 + 16) = *reinterpret_cast<unsigned long long*>(&by[8]);
    } else {
        unsigned tid = (blockIdx.x - 9216) * 256 + threadIdx.x;
        int arr = tid >> 16;                      // 65536 threads per matrix
        unsigned idx = tid & 65535u;
        const float* s = (arr == 0) ? Wq : (arr == 1) ? Wk : Wv;
        unsigned char* d = (arr == 0) ? Wq8 : (arr == 1) ? Wk8 : Wv8;
        unsigned char by[16];
#pragma unroll
        for (int i = 0; i < 4; ++i) {
            f32x4 a = *reinterpret_cast<const f32x4*>(s + (size_t)idx * 16 + i * 4);
#pragma unroll
            for (int j = 0; j < 4; ++j) by[i * 4 + j] = f2fp8(a[j] * 64.f);
        }
        int o = (idx & 3) * 16;
        int s0 = (o < 32) ? 2 * o : 2 * (o - 32) + 8;
        unsigned char* base = d + (size_t)(idx >> 2) * 64;
        *reinterpret_cast<unsigned long long*>(base + s0)      = *reinterpret_cast<unsigned long long*>(&by[0]);
        *reinterpret_cast<unsigned long long*>(base + s0 + 16) = *reinterpret_cast<unsigned long long*>(&by[8]);
    }
}

// ---------------------------------------- gemm256 (fp8, round-8 schedule) ----
// blocks [0,1024): K|V (A=LNx8, W=Wk8|Wv8, nt>=4 -> V transposed).
// blocks [1024,1088): Q (A=LNh8, W=Wq8).
// 16 K-tiles of 64; per kt 2 phases (mq): {8 ds_read_b128 (i64 pairs) ;
// stage 2 gloads ; barrier ; lgkmcnt(0) ; 32 fp8 MFMA ; [mq==1: vmcnt(0)] ;
// barrier}. LDS 64KB. Output = acc/64 + bias (W was scaled x64).
__global__ __launch_bounds__(512, 2) void gemm256(
    const unsigned char* __restrict__ A8, const unsigned char* __restrict__ Ah8,
    const unsigned char* __restrict__ W8, const unsigned char* __restrict__ Wq8,
    const float* __restrict__ bk, const float* __restrict__ bv, const float* __restrict__ bq,
    unsigned short* __restrict__ Cn, unsigned short* __restrict__ Vt, unsigned short* __restrict__ Qm)
{
    __shared__ __align__(16) char smemc[65536];   // A slots @0,16384; B @32768,49152

    int t = threadIdx.x, lane = t & 63, w = t >> 6, g = lane >> 4, lr = lane & 15;
    int wr = w >> 2, wcn = w & 3;
    int R0 = wr * 128, C0 = wcn * 64;

    int id = blockIdx.x;
    int m0, n0, trans = 0;
    const unsigned char *Ab_, *Wb_;
    const float* bias;
    unsigned short* Cout;
    if (id < 1024) {
        int xcd = id & 7, ord = id >> 3;
        int mt = xcd * 16 + ord / 8;
        int nt = ord % 8;
        m0 = mt * 256; n0 = nt * 256;
        Ab_ = A8; Wb_ = W8;
        if (nt < 4) { bias = bk; Cout = Cn; }
        else        { bias = bv; Cout = Vt; trans = 1; }
    } else {
        int id2 = id - 1024;
        int mt = id2 & 15, nt = id2 >> 4;
        m0 = mt * 256; n0 = nt * 256;
        Ab_ = Ah8; Wb_ = Wq8;
        bias = bq; Cout = Qm;
    }

    const unsigned char* Ap = Ab_ + (size_t)m0 * 1024;
    const unsigned char* Wp = Wb_ + (size_t)n0 * 1024;

    f32x4 acc[8][4];
#pragma unroll
    for (int i = 0; i < 8; ++i)
#pragma unroll
        for (int j = 0; j < 4; ++j) acc[i][j] = (f32x4)0.f;

    // one 8KB gload set; q: 0=A h0, 1=A h1, 2=B h0, 3=B h1
    auto STAGE1 = [&](int slot, int kt, int q) {
        const unsigned char* P = (q < 2) ? Ap : Wp;
        char* ldsb = smemc + ((q < 2) ? 0 : 32768) + slot * 16384 + (q & 1) * 8192;
        int r = (q & 1) * 128 + (t >> 2);
        const char* gp = (const char*)(P + (size_t)r * 1024 + kt * 64 + (t & 3) * 16);
        GLOAD16(gp, ldsb + (t >> 2) * 64 + (t & 3) * 16);
    };

    STAGE1(0, 0, 0); STAGE1(0, 0, 1); STAGE1(0, 0, 2); STAGE1(0, 0, 3);
    asm volatile("s_waitcnt vmcnt(0)" ::: "memory");
    __builtin_amdgcn_s_barrier();

    for (int kt = 0; kt < 16; ++kt) {
        const int cs = kt & 1;
        const char* Ab = smemc + cs * 16384;
        const char* Bb = smemc + 32768 + cs * 16384;
#pragma unroll
        for (int mq = 0; mq < 2; ++mq) {
            i64x2 af[4], bf[4];
#pragma unroll
            for (int a = 0; a < 4; ++a) {
                int r = R0 + mq * 64 + a * 16 + lr;
                af[a] = *reinterpret_cast<const i64x2*>(Ab + r * 64 + g * 16);
            }
#pragma unroll
            for (int ni = 0; ni < 4; ++ni) {
                int r = C0 + ni * 16 + lr;
                bf[ni] = *reinterpret_cast<const i64x2*>(Bb + r * 64 + g * 16);
            }
            if (kt < 15) { STAGE1(cs ^ 1, kt + 1, mq * 2); STAGE1(cs ^ 1, kt + 1, mq * 2 + 1); }
            __builtin_amdgcn_sched_barrier(0);
            __builtin_amdgcn_s_barrier();
            asm volatile("s_waitcnt lgkmcnt(0)" ::: "memory");
            __builtin_amdgcn_sched_barrier(0);
            __builtin_amdgcn_s_setprio(1);
#pragma unroll
            for (int a = 0; a < 4; ++a)
#pragma unroll
                for (int ni = 0; ni < 4; ++ni) {
                    acc[mq * 4 + a][ni] = __builtin_amdgcn_mfma_f32_16x16x32_fp8_fp8(
                        af[a][0], bf[ni][0], acc[mq * 4 + a][ni], 0, 0, 0);
                    acc[mq * 4 + a][ni] = __builtin_amdgcn_mfma_f32_16x16x32_fp8_fp8(
                        af[a][1], bf[ni][1], acc[mq * 4 + a][ni], 0, 0, 0);
                }
            __builtin_amdgcn_s_setprio(0);
            if (mq == 1) asm volatile("s_waitcnt vmcnt(0)" ::: "memory");
            __builtin_amdgcn_sched_barrier(0);
            __builtin_amdgcn_s_barrier();
        }
    }
    __syncthreads();

    const float SC = 0.015625f;   // 1/64 (W scale)
    unsigned short* CtS = (unsigned short*)smemc;   // [64][272] = 34.8KB
    if (!trans) {
#pragma unroll
        for (int ch = 0; ch < 4; ++ch) {
            if (ch) __syncthreads();
            if (wr == (ch >> 1)) {
                int ma = (ch & 1) * 4;
#pragma unroll
                for (int ni = 0; ni < 4; ++ni) {
                    int c = C0 + ni * 16 + lr;
                    float bvv = bias[n0 + c];
#pragma unroll
                    for (int a = 0; a < 4; ++a)
#pragma unroll
                        for (int j = 0; j < 4; ++j)
                            CtS[(a * 16 + g * 4 + j) * 272 + c] = f2bf(acc[ma + a][ni][j] * SC + bvv);
                }
            }
            __syncthreads();
#pragma unroll
            for (int it = 0; it < 4; ++it) {
                int u2 = it * 512 + t;
                int row = u2 >> 5, c16 = u2 & 31;
                *reinterpret_cast<short8*>(Cout + (size_t)(m0 + ch * 64 + row) * 1024 + n0 + c16 * 8) =
                    *reinterpret_cast<const short8*>(&CtS[row * 272 + c16 * 8]);
            }
        }
    } else {
        int nt = n0 >> 8;                      // 4..7
        int hbase = (nt - 4) * 2;
        int b = m0 >> 12, kv0 = m0 & 4095;
#pragma unroll
        for (int ch = 0; ch < 4; ++ch) {
            if (ch) __syncthreads();
            if (wcn == ch) {
#pragma unroll
                for (int ni = 0; ni < 4; ++ni) {
                    int dl = ni * 16 + lr;             // 0..63
                    float bvv = bias[(nt - 4) * 256 + ch * 64 + dl];
#pragma unroll
                    for (int mi = 0; mi < 8; ++mi)
#pragma unroll
                        for (int j = 0; j < 4; ++j)
                            CtS[dl * 272 + R0 + mi * 16 + g * 4 + j] = f2bf(acc[mi][ni][j] * SC + bvv);
                }
            }
            __syncthreads();
            int hh = hbase + (ch >> 1), dbase = (ch & 1) * 64;
            unsigned short* dst = Cout + ((size_t)(b * 8 + hh) * 128 + dbase) * 4096 + kv0;
#pragma unroll
            for (int it = 0; it < 4; ++it) {
                int u2 = it * 512 + t;
                int row = u2 >> 5, c8 = u2 & 31;
                *reinterpret_cast<short8*>(dst + (size_t)row * 4096 + c8 * 8) =
                    *reinterpret_cast<const short8*>(&CtS[row * 272 + c8 * 8]);
            }
        }
    }
}

// ----------------------------------------------------------- attention ----
// unchanged (verified): swapped QK^T, defer-max, packed P, dbuf gload_lds.
__global__ __launch_bounds__(256, 2) void attn_kernel(
    const unsigned short* __restrict__ Qm, const unsigned short* __restrict__ Km,
    const unsigned short* __restrict__ VtG, const float* __restrict__ hidden,
    float* __restrict__ out)
{
    __shared__ __align__(16) unsigned short Kl[2][64 * 128];
    __shared__ __align__(16) unsigned short Vt[2][128 * 64];
    __shared__ __align__(16) unsigned short Pl[64 * 64];

    int t = threadIdx.x, lane = t & 63, w = t >> 6, g = lane >> 4, lr = lane & 15;
    int id = blockIdx.x;
    int swz = (id & 7) * 64 + (id >> 3);
    int qt = swz & 7, h = (swz >> 3) & 7, b = swz >> 6;

    short8 qf[4];
#pragma unroll
    for (int kk = 0; kk < 4; ++kk)
        qf[kk] = *reinterpret_cast<const short8*>(
            Qm + (size_t)(b * 512 + qt * 64 + w * 16 + lr) * 1024 + h * 128 + kk * 32 + g * 8);
    asm volatile("s_waitcnt vmcnt(0)" ::: "memory");

    float m2 = 0.f;
    float l = 0.f;
    f32x4 oacc[8];
#pragma unroll
    for (int nf = 0; nf < 8; ++nf) oacc[nf] = (f32x4)0.f;

    const float SCALE = 0.08838834764831845f;
    const float LOG2E = 1.4426950408889634f;
    const float K1 = SCALE * LOG2E;
    const float THR2 = 11.5f;

    size_t kbase = (size_t)b * 4096 * 1024 + h * 128;
    size_t vbase = ((size_t)(b * 8 + h)) * 128 * 4096;

    auto STAGE_K = [&](int buf, int c) {
        int kv0 = c * 64;
#pragma unroll
        for (int i = 0; i < 4; ++i) {
            int rb = w * 16 + i * 4;
            int row = rb + (lane >> 4);
            int cb = ((lane & 15) * 16) ^ ((row & 7) << 4);
            const char* gp = (const char*)(Km + kbase + (size_t)(kv0 + row) * 1024) + cb;
            GLOAD16(gp, &Kl[buf][rb * 128]);
        }
    };
    auto STAGE_V = [&](int buf, int c) {
        int kv0 = c * 64;
#pragma unroll
        for (int i = 0; i < 4; ++i) {
            int db = w * 32 + i * 8;
            int d = db + (lane >> 3);
            int cb = ((lane & 7) * 16) ^ ((d & 7) << 4);
            const char* gp = (const char*)(VtG + vbase + (size_t)d * 4096 + kv0) + cb;
            GLOAD16(gp, &Vt[buf][db * 64]);
        }
    };

    STAGE_K(0, 0); STAGE_V(0, 0);

    for (int c = 0; c < 64; ++c) {
        int cur = c & 1;
        asm volatile("s_waitcnt vmcnt(0) lgkmcnt(0)" ::: "memory");
        __builtin_amdgcn_sched_barrier(0);
        __builtin_amdgcn_s_barrier();
        if (c < 63) { STAGE_K(cur ^ 1, c + 1); STAGE_V(cur ^ 1, c + 1); }

        f32x4 sacc[4];
#pragma unroll
        for (int nf = 0; nf < 4; ++nf) sacc[nf] = (f32x4)0.f;
#pragma unroll
        for (int kk = 0; kk < 4; ++kk) {
            int cb0 = kk * 64 + g * 16;
            short8 kf[4];
#pragma unroll
            for (int nf = 0; nf < 4; ++nf) {
                int row = nf * 16 + lr;
                kf[nf] = *reinterpret_cast<const short8*>(
                    (const char*)&Kl[cur][0] + row * 256 + (cb0 ^ ((row & 7) << 4)));
            }
            __builtin_amdgcn_s_setprio(1);
#pragma unroll
            for (int nf = 0; nf < 4; ++nf)
                sacc[nf] = __builtin_amdgcn_mfma_f32_16x16x32_bf16(kf[nf], qf[kk], sacc[nf], 0, 0, 0);
            __builtin_amdgcn_s_setprio(0);
        }

        float smax = sacc[0][0];
#pragma unroll
        for (int nf = 0; nf < 4; ++nf)
#pragma unroll
            for (int j = 0; j < 4; ++j) smax = fmaxf(smax, sacc[nf][j]);
        float s2max = smax * K1;
        if (!__all(s2max <= m2 + THR2)) {
            float rm = s2max;
            rm = fmaxf(rm, __shfl_xor(rm, 16));
            rm = fmaxf(rm, __shfl_xor(rm, 32));
            float m2n = fmaxf(m2, rm);
            float corr = exp2f(m2 - m2n);
            l *= corr;
            m2 = m2n;
#pragma unroll
            for (int j = 0; j < 4; ++j) {
                float cj = __shfl(corr, g * 4 + j);
#pragma unroll
                for (int nf = 0; nf < 8; ++nf) oacc[nf][j] *= cj;
            }
        }
        int prow = w * 16 + lr;
        int rsw = (lr & 7) << 4;
#pragma unroll
        for (int nf = 0; nf < 4; ++nf) {
            float p0 = exp2f(sacc[nf][0] * K1 - m2);
            float p1 = exp2f(sacc[nf][1] * K1 - m2);
            float p2 = exp2f(sacc[nf][2] * K1 - m2);
            float p3 = exp2f(sacc[nf][3] * K1 - m2);
            l += (p0 + p1) + (p2 + p3);
            bf16x4 pk;
            pk[0] = (short)f2bf(p0); pk[1] = (short)f2bf(p1);
            pk[2] = (short)f2bf(p2); pk[3] = (short)f2bf(p3);
            *reinterpret_cast<bf16x4*>(
                (char*)Pl + prow * 128 + ((nf * 32 + g * 8) ^ rsw)) = pk;
        }
        asm volatile("s_waitcnt lgkmcnt(0)" ::: "memory");
        __builtin_amdgcn_sched_barrier(0);

#pragma unroll
        for (int kp = 0; kp < 2; ++kp) {
            int cb0 = kp * 64 + g * 16;
            short8 pa = *reinterpret_cast<const short8*>(
                (const char*)Pl + prow * 128 + (cb0 ^ rsw));
#pragma unroll
            for (int nf = 0; nf < 8; ++nf) {
                int d = nf * 16 + lr;
                short8 vb = *reinterpret_cast<const short8*>(
                    (const char*)&Vt[cur][0] + d * 128 + (cb0 ^ ((d & 7) << 4)));
                oacc[nf] = __builtin_amdgcn_mfma_f32_16x16x32_bf16(pa, vb, oacc[nf], 0, 0, 0);
            }
        }
    }

    l += __shfl_xor(l, 16);
    l += __shfl_xor(l, 32);
#pragma unroll
    for (int j = 0; j < 4; ++j) {
        float lj = __shfl(l, g * 4 + j);
        float inv = 1.f / lj;
        int q = qt * 64 + w * 16 + g * 4 + j;
        size_t base = (size_t)(b * 512 + q) * 1024 + h * 128;
#pragma unroll
        for (int nf = 0; nf < 8; ++nf) {
            int d = nf * 16 + lr;
            out[base + d] = hidden[base + d] + oacc[nf][j] * inv;
        }
    }
}

// ---------------------------------------------------------------- host ----
extern "C" void kernel_launch(void* const* d_in, const int* in_sizes, int n_in,
                              void* d_out, int out_size, void* d_ws, size_t ws_size,
                              hipStream_t stream) {
    const float* hidden = (const float*)d_in[0];
    const float* inputs = (const float*)d_in[1];
    const float* ln1w   = (const float*)d_in[2];
    const float* ln1b   = (const float*)d_in[3];
    const float* ln2w   = (const float*)d_in[4];
    const float* ln2b   = (const float*)d_in[5];
    const float* Wq     = (const float*)d_in[6];
    const float* bq     = (const float*)d_in[7];
    const float* Wk     = (const float*)d_in[8];
    const float* bk     = (const float*)d_in[9];
    const float* Wv     = (const float*)d_in[10];
    const float* bv     = (const float*)d_in[11];
    float* out = (float*)d_out;
    char* ws = (char*)d_ws;

    unsigned char* LNh8 = (unsigned char*)ws;          // 4096x1024 fp8
    unsigned char* LNx8 = LNh8 + 4194304;              // 32768x1024 fp8
    unsigned char* Wq8  = LNx8 + 33554432;             // Wq8, then Wk8|Wv8 contiguous
    unsigned char* Wk8  = Wq8 + 1048576;
    unsigned char* Wv8  = Wk8 + 1048576;
    unsigned short* Qm  = (unsigned short*)(Wv8 + 1048576);   // 4096x1024 bf16
    unsigned short* Km  = Qm + 4194304;                // 32768x1024 bf16
    unsigned short* VtG = Km + 33554432;               // [b][h][128 d][4096 kv] bf16

    prep<<<dim3(9984), dim3(256), 0, stream>>>(
        hidden, inputs, ln1w, ln1b, ln2w, ln2b, Wq, Wk, Wv, LNh8, LNx8, Wq8, Wk8, Wv8);
    gemm256<<<dim3(1088), dim3(512), 0, stream>>>(
        LNx8, LNh8, Wk8, Wq8, bk, bv, bq, Km, VtG, Qm);
    attn_kernel<<<dim3(512), dim3(256), 0, stream>>>(Qm, Km, VtG, hidden, out);
}

// Round 14
// 298.441 us; speedup vs baseline: 4.1152x; 1.0445x over previous
//
#include <hip/hip_runtime.h>
#include <hip/hip_fp8.h>

typedef __attribute__((ext_vector_type(8))) short short8;
typedef __attribute__((ext_vector_type(4))) short bf16x4;
typedef __attribute__((ext_vector_type(4))) float f32x4;
typedef __attribute__((ext_vector_type(2))) long i64x2;

#define DEV __device__ __forceinline__

DEV unsigned short f2bf(float f) {
    unsigned int u = __builtin_bit_cast(unsigned int, f);
    u += 0x7fffu + ((u >> 16) & 1u);
    return (unsigned short)(u >> 16);
}

DEV unsigned char f2fp8(float f) {
    return __hip_fp8_e4m3(f).__x;
}

#define GLOAD16(gp, lp)                                                        \
    __builtin_amdgcn_global_load_lds(                                          \
        (const __attribute__((address_space(1))) void*)(gp),                   \
        (__attribute__((address_space(3))) void*)(lp), 16, 0, 0)

// ---------------------------------------------------- prep (LN+convert, fp8) ----
// (unchanged from round 13)
__global__ __launch_bounds__(256) void prep(
    const float* __restrict__ hidden, const float* __restrict__ inputs,
    const float* __restrict__ ln1w, const float* __restrict__ ln1b,
    const float* __restrict__ ln2w, const float* __restrict__ ln2b,
    const float* __restrict__ Wq, const float* __restrict__ Wk, const float* __restrict__ Wv,
    unsigned char* __restrict__ LNh8, unsigned char* __restrict__ LNx8,
    unsigned char* __restrict__ Wq8, unsigned char* __restrict__ Wk8, unsigned char* __restrict__ Wv8)
{
    if (blockIdx.x < 9216) {
        int row = blockIdx.x * 4 + (threadIdx.x >> 6);
        int lane = threadIdx.x & 63;
        const float *src, *wp, *bp; unsigned char* dst;
        if (row < 4096) { src = hidden + (size_t)row * 1024; wp = ln1w; bp = ln1b; dst = LNh8 + (size_t)row * 1024; }
        else { int r = row - 4096; src = inputs + (size_t)r * 1024; wp = ln2w; bp = ln2b; dst = LNx8 + (size_t)r * 1024; }

        f32x4 v[4];
        float s = 0.f, ss = 0.f;
#pragma unroll
        for (int i = 0; i < 4; ++i) {
            v[i] = *reinterpret_cast<const f32x4*>(src + lane * 16 + i * 4);
#pragma unroll
            for (int j = 0; j < 4; ++j) { s += v[i][j]; ss += v[i][j] * v[i][j]; }
        }
#pragma unroll
        for (int off = 32; off >= 1; off >>= 1) { s += __shfl_xor(s, off); ss += __shfl_xor(ss, off); }
        float mu = s * (1.f / 1024.f);
        float var = fmaxf(ss * (1.f / 1024.f) - mu * mu, 0.f);
        float rs = rsqrtf(var + 1e-5f);

        unsigned char by[16];
#pragma unroll
        for (int i = 0; i < 4; ++i) {
            f32x4 wv = *reinterpret_cast<const f32x4*>(wp + lane * 16 + i * 4);
            f32x4 bv = *reinterpret_cast<const f32x4*>(bp + lane * 16 + i * 4);
#pragma unroll
            for (int j = 0; j < 4; ++j)
                by[i * 4 + j] = f2fp8((v[i][j] - mu) * rs * wv[j] + bv[j]);
        }
        int o = (lane * 16) & 63;
        int s0 = (o < 32) ? 2 * o : 2 * (o - 32) + 8;
        unsigned char* base = dst + (lane >> 2) * 64;
        *reinterpret_cast<unsigned long long*>(base + s0)      = *reinterpret_cast<unsigned long long*>(&by[0]);
        *reinterpret_cast<unsigned long long*>(base + s0 + 16) = *reinterpret_cast<unsigned long long*>(&by[8]);
    } else {
        unsigned tid = (blockIdx.x - 9216) * 256 + threadIdx.x;
        int arr = tid >> 16;
        unsigned idx = tid & 65535u;
        const float* s = (arr == 0) ? Wq : (arr == 1) ? Wk : Wv;
        unsigned char* d = (arr == 0) ? Wq8 : (arr == 1) ? Wk8 : Wv8;
        unsigned char by[16];
#pragma unroll
        for (int i = 0; i < 4; ++i) {
            f32x4 a = *reinterpret_cast<const f32x4*>(s + (size_t)idx * 16 + i * 4);
#pragma unroll
            for (int j = 0; j < 4; ++j) by[i * 4 + j] = f2fp8(a[j] * 64.f);
        }
        int o = (idx & 3) * 16;
        int s0 = (o < 32) ? 2 * o : 2 * (o - 32) + 8;
        unsigned char* base = d + (size_t)(idx >> 2) * 64;
        *reinterpret_cast<unsigned long long*>(base + s0)      = *reinterpret_cast<unsigned long long*>(&by[0]);
        *reinterpret_cast<unsigned long long*>(base + s0 + 16) = *reinterpret_cast<unsigned long long*>(&by[8]);
    }
}

// ---------------------------------------- gemm256 (fp8 + 4-slot XOR swizzle) ----
// LDS tile row r (64B) slot s holds global chunk s ^ ((r>>1)&3).
// Staging: linear dest, source chunk permuted (same involution).
// Fragment read of logical chunk g: slot g ^ ((lr>>1)&3) -> quarter-wave lanes
// spread over 8 slots/128B (2-way, free) instead of 2 slots (8-way).
__global__ __launch_bounds__(512, 2) void gemm256(
    const unsigned char* __restrict__ A8, const unsigned char* __restrict__ Ah8,
    const unsigned char* __restrict__ W8, const unsigned char* __restrict__ Wq8,
    const float* __restrict__ bk, const float* __restrict__ bv, const float* __restrict__ bq,
    unsigned short* __restrict__ Cn, unsigned short* __restrict__ Vt, unsigned short* __restrict__ Qm)
{
    __shared__ __align__(16) char smemc[65536];   // A slots @0,16384; B @32768,49152

    int t = threadIdx.x, lane = t & 63, w = t >> 6, g = lane >> 4, lr = lane & 15;
    int wr = w >> 2, wcn = w & 3;
    int R0 = wr * 128, C0 = wcn * 64;

    int id = blockIdx.x;
    int m0, n0, trans = 0;
    const unsigned char *Ab_, *Wb_;
    const float* bias;
    unsigned short* Cout;
    if (id < 1024) {
        int xcd = id & 7, ord = id >> 3;
        int mt = xcd * 16 + ord / 8;
        int nt = ord % 8;
        m0 = mt * 256; n0 = nt * 256;
        Ab_ = A8; Wb_ = W8;
        if (nt < 4) { bias = bk; Cout = Cn; }
        else        { bias = bv; Cout = Vt; trans = 1; }
    } else {
        int id2 = id - 1024;
        int mt = id2 & 15, nt = id2 >> 4;
        m0 = mt * 256; n0 = nt * 256;
        Ab_ = Ah8; Wb_ = Wq8;
        bias = bq; Cout = Qm;
    }

    const unsigned char* Ap = Ab_ + (size_t)m0 * 1024;
    const unsigned char* Wp = Wb_ + (size_t)n0 * 1024;

    f32x4 acc[8][4];
#pragma unroll
    for (int i = 0; i < 8; ++i)
#pragma unroll
        for (int j = 0; j < 4; ++j) acc[i][j] = (f32x4)0.f;

    // staging: linear LDS dest (lane*16); source chunk = (t&3) ^ ((t>>3)&3)
    int schunk = (t & 3) ^ ((t >> 3) & 3);
    auto STAGE1 = [&](int slot, int kt, int q) {
        const unsigned char* P = (q < 2) ? Ap : Wp;
        char* ldsb = smemc + ((q < 2) ? 0 : 32768) + slot * 16384 + (q & 1) * 8192;
        int r = (q & 1) * 128 + (t >> 2);
        const char* gp = (const char*)(P + (size_t)r * 1024 + kt * 64 + schunk * 16);
        GLOAD16(gp, ldsb + (t >> 2) * 64 + (t & 3) * 16);
    };

    STAGE1(0, 0, 0); STAGE1(0, 0, 1); STAGE1(0, 0, 2); STAGE1(0, 0, 3);
    asm volatile("s_waitcnt vmcnt(0)" ::: "memory");
    __builtin_amdgcn_s_barrier();

    int xr = (lr >> 1) & 3;                      // read-side slot XOR
    int slA = (g ^ xr) * 16;

    for (int kt = 0; kt < 16; ++kt) {
        const int cs = kt & 1;
        const char* Ab = smemc + cs * 16384;
        const char* Bb = smemc + 32768 + cs * 16384;
#pragma unroll
        for (int mq = 0; mq < 2; ++mq) {
            i64x2 af[4], bf[4];
#pragma unroll
            for (int a = 0; a < 4; ++a) {
                int r = R0 + mq * 64 + a * 16 + lr;
                af[a] = *reinterpret_cast<const i64x2*>(Ab + r * 64 + slA);
            }
#pragma unroll
            for (int ni = 0; ni < 4; ++ni) {
                int r = C0 + ni * 16 + lr;
                bf[ni] = *reinterpret_cast<const i64x2*>(Bb + r * 64 + slA);
            }
            if (kt < 15) { STAGE1(cs ^ 1, kt + 1, mq * 2); STAGE1(cs ^ 1, kt + 1, mq * 2 + 1); }
            __builtin_amdgcn_sched_barrier(0);
            __builtin_amdgcn_s_barrier();
            asm volatile("s_waitcnt lgkmcnt(0)" ::: "memory");
            __builtin_amdgcn_sched_barrier(0);
            __builtin_amdgcn_s_setprio(1);
#pragma unroll
            for (int a = 0; a < 4; ++a)
#pragma unroll
                for (int ni = 0; ni < 4; ++ni) {
                    acc[mq * 4 + a][ni] = __builtin_amdgcn_mfma_f32_16x16x32_fp8_fp8(
                        af[a][0], bf[ni][0], acc[mq * 4 + a][ni], 0, 0, 0);
                    acc[mq * 4 + a][ni] = __builtin_amdgcn_mfma_f32_16x16x32_fp8_fp8(
                        af[a][1], bf[ni][1], acc[mq * 4 + a][ni], 0, 0, 0);
                }
            __builtin_amdgcn_s_setprio(0);
            if (mq == 1) asm volatile("s_waitcnt vmcnt(0)" ::: "memory");
            __builtin_amdgcn_sched_barrier(0);
            __builtin_amdgcn_s_barrier();
        }
    }
    __syncthreads();

    const float SC = 0.015625f;   // 1/64 (W scale)
    unsigned short* CtS = (unsigned short*)smemc;   // [64][272]
    if (!trans) {
#pragma unroll
        for (int ch = 0; ch < 4; ++ch) {
            if (ch) __syncthreads();
            if (wr == (ch >> 1)) {
                int ma = (ch & 1) * 4;
#pragma unroll
                for (int ni = 0; ni < 4; ++ni) {
                    int c = C0 + ni * 16 + lr;
                    float bvv = bias[n0 + c];
#pragma unroll
                    for (int a = 0; a < 4; ++a)
#pragma unroll
                        for (int j = 0; j < 4; ++j)
                            CtS[(a * 16 + g * 4 + j) * 272 + c] = f2bf(acc[ma + a][ni][j] * SC + bvv);
                }
            }
            __syncthreads();
#pragma unroll
            for (int it = 0; it < 4; ++it) {
                int u2 = it * 512 + t;
                int row = u2 >> 5, c16 = u2 & 31;
                *reinterpret_cast<short8*>(Cout + (size_t)(m0 + ch * 64 + row) * 1024 + n0 + c16 * 8) =
                    *reinterpret_cast<const short8*>(&CtS[row * 272 + c16 * 8]);
            }
        }
    } else {
        int nt = n0 >> 8;                      // 4..7
        int hbase = (nt - 4) * 2;
        int b = m0 >> 12, kv0 = m0 & 4095;
#pragma unroll
        for (int ch = 0; ch < 4; ++ch) {
            if (ch) __syncthreads();
            if (wcn == ch) {
#pragma unroll
                for (int ni = 0; ni < 4; ++ni) {
                    int dl = ni * 16 + lr;
                    float bvv = bias[(nt - 4) * 256 + ch * 64 + dl];
#pragma unroll
                    for (int mi = 0; mi < 8; ++mi)
#pragma unroll
                        for (int j = 0; j < 4; ++j)
                            CtS[dl * 272 + R0 + mi * 16 + g * 4 + j] = f2bf(acc[mi][ni][j] * SC + bvv);
                }
            }
            __syncthreads();
            int hh = hbase + (ch >> 1), dbase = (ch & 1) * 64;
            unsigned short* dst = Cout + ((size_t)(b * 8 + hh) * 128 + dbase) * 4096 + kv0;
#pragma unroll
            for (int it = 0; it < 4; ++it) {
                int u2 = it * 512 + t;
                int row = u2 >> 5, c8 = u2 & 31;
                *reinterpret_cast<short8*>(dst + (size_t)row * 4096 + c8 * 8) =
                    *reinterpret_cast<const short8*>(&CtS[row * 272 + c8 * 8]);
            }
        }
    }
}

// ----------------------------------------------------------- attention ----
// unchanged (verified): swapped QK^T, defer-max, packed P, dbuf gload_lds.
__global__ __launch_bounds__(256, 2) void attn_kernel(
    const unsigned short* __restrict__ Qm, const unsigned short* __restrict__ Km,
    const unsigned short* __restrict__ VtG, const float* __restrict__ hidden,
    float* __restrict__ out)
{
    __shared__ __align__(16) unsigned short Kl[2][64 * 128];
    __shared__ __align__(16) unsigned short Vt[2][128 * 64];
    __shared__ __align__(16) unsigned short Pl[64 * 64];

    int t = threadIdx.x, lane = t & 63, w = t >> 6, g = lane >> 4, lr = lane & 15;
    int id = blockIdx.x;
    int swz = (id & 7) * 64 + (id >> 3);
    int qt = swz & 7, h = (swz >> 3) & 7, b = swz >> 6;

    short8 qf[4];
#pragma unroll
    for (int kk = 0; kk < 4; ++kk)
        qf[kk] = *reinterpret_cast<const short8*>(
            Qm + (size_t)(b * 512 + qt * 64 + w * 16 + lr) * 1024 + h * 128 + kk * 32 + g * 8);
    asm volatile("s_waitcnt vmcnt(0)" ::: "memory");

    float m2 = 0.f;
    float l = 0.f;
    f32x4 oacc[8];
#pragma unroll
    for (int nf = 0; nf < 8; ++nf) oacc[nf] = (f32x4)0.f;

    const float SCALE = 0.08838834764831845f;
    const float LOG2E = 1.4426950408889634f;
    const float K1 = SCALE * LOG2E;
    const float THR2 = 11.5f;

    size_t kbase = (size_t)b * 4096 * 1024 + h * 128;
    size_t vbase = ((size_t)(b * 8 + h)) * 128 * 4096;

    auto STAGE_K = [&](int buf, int c) {
        int kv0 = c * 64;
#pragma unroll
        for (int i = 0; i < 4; ++i) {
            int rb = w * 16 + i * 4;
            int row = rb + (lane >> 4);
            int cb = ((lane & 15) * 16) ^ ((row & 7) << 4);
            const char* gp = (const char*)(Km + kbase + (size_t)(kv0 + row) * 1024) + cb;
            GLOAD16(gp, &Kl[buf][rb * 128]);
        }
    };
    auto STAGE_V = [&](int buf, int c) {
        int kv0 = c * 64;
#pragma unroll
        for (int i = 0; i < 4; ++i) {
            int db = w * 32 + i * 8;
            int d = db + (lane >> 3);
            int cb = ((lane & 7) * 16) ^ ((d & 7) << 4);
            const char* gp = (const char*)(VtG + vbase + (size_t)d * 4096 + kv0) + cb;
            GLOAD16(gp, &Vt[buf][db * 64]);
        }
    };

    STAGE_K(0, 0); STAGE_V(0, 0);

    for (int c = 0; c < 64; ++c) {
        int cur = c & 1;
        asm volatile("s_waitcnt vmcnt(0) lgkmcnt(0)" ::: "memory");
        __builtin_amdgcn_sched_barrier(0);
        __builtin_amdgcn_s_barrier();
        if (c < 63) { STAGE_K(cur ^ 1, c + 1); STAGE_V(cur ^ 1, c + 1); }

        f32x4 sacc[4];
#pragma unroll
        for (int nf = 0; nf < 4; ++nf) sacc[nf] = (f32x4)0.f;
#pragma unroll
        for (int kk = 0; kk < 4; ++kk) {
            int cb0 = kk * 64 + g * 16;
            short8 kf[4];
#pragma unroll
            for (int nf = 0; nf < 4; ++nf) {
                int row = nf * 16 + lr;
                kf[nf] = *reinterpret_cast<const short8*>(
                    (const char*)&Kl[cur][0] + row * 256 + (cb0 ^ ((row & 7) << 4)));
            }
            __builtin_amdgcn_s_setprio(1);
#pragma unroll
            for (int nf = 0; nf < 4; ++nf)
                sacc[nf] = __builtin_amdgcn_mfma_f32_16x16x32_bf16(kf[nf], qf[kk], sacc[nf], 0, 0, 0);
            __builtin_amdgcn_s_setprio(0);
        }

        float smax = sacc[0][0];
#pragma unroll
        for (int nf = 0; nf < 4; ++nf)
#pragma unroll
            for (int j = 0; j < 4; ++j) smax = fmaxf(smax, sacc[nf][j]);
        float s2max = smax * K1;
        if (!__all(s2max <= m2 + THR2)) {
            float rm = s2max;
            rm = fmaxf(rm, __shfl_xor(rm, 16));
            rm = fmaxf(rm, __shfl_xor(rm, 32));
            float m2n = fmaxf(m2, rm);
            float corr = exp2f(m2 - m2n);
            l *= corr;
            m2 = m2n;
#pragma unroll
            for (int j = 0; j < 4; ++j) {
                float cj = __shfl(corr, g * 4 + j);
#pragma unroll
                for (int nf = 0; nf < 8; ++nf) oacc[nf][j] *= cj;
            }
        }
        int prow = w * 16 + lr;
        int rsw = (lr & 7) << 4;
#pragma unroll
        for (int nf = 0; nf < 4; ++nf) {
            float p0 = exp2f(sacc[nf][0] * K1 - m2);
            float p1 = exp2f(sacc[nf][1] * K1 - m2);
            float p2 = exp2f(sacc[nf][2] * K1 - m2);
            float p3 = exp2f(sacc[nf][3] * K1 - m2);
            l += (p0 + p1) + (p2 + p3);
            bf16x4 pk;
            pk[0] = (short)f2bf(p0); pk[1] = (short)f2bf(p1);
            pk[2] = (short)f2bf(p2); pk[3] = (short)f2bf(p3);
            *reinterpret_cast<bf16x4*>(
                (char*)Pl + prow * 128 + ((nf * 32 + g * 8) ^ rsw)) = pk;
        }
        asm volatile("s_waitcnt lgkmcnt(0)" ::: "memory");
        __builtin_amdgcn_sched_barrier(0);

#pragma unroll
        for (int kp = 0; kp < 2; ++kp) {
            int cb0 = kp * 64 + g * 16;
            short8 pa = *reinterpret_cast<const short8*>(
                (const char*)Pl + prow * 128 + (cb0 ^ rsw));
#pragma unroll
            for (int nf = 0; nf < 8; ++nf) {
                int d = nf * 16 + lr;
                short8 vb = *reinterpret_cast<const short8*>(
                    (const char*)&Vt[cur][0] + d * 128 + (cb0 ^ ((d & 7) << 4)));
                oacc[nf] = __builtin_amdgcn_mfma_f32_16x16x32_bf16(pa, vb, oacc[nf], 0, 0, 0);
            }
        }
    }

    l += __shfl_xor(l, 16);
    l += __shfl_xor(l, 32);
#pragma unroll
    for (int j = 0; j < 4; ++j) {
        float lj = __shfl(l, g * 4 + j);
        float inv = 1.f / lj;
        int q = qt * 64 + w * 16 + g * 4 + j;
        size_t base = (size_t)(b * 512 + q) * 1024 + h * 128;
#pragma unroll
        for (int nf = 0; nf < 8; ++nf) {
            int d = nf * 16 + lr;
            out[base + d] = hidden[base + d] + oacc[nf][j] * inv;
        }
    }
}

// ---------------------------------------------------------------- host ----
extern "C" void kernel_launch(void* const* d_in, const int* in_sizes, int n_in,
                              void* d_out, int out_size, void* d_ws, size_t ws_size,
                              hipStream_t stream) {
    const float* hidden = (const float*)d_in[0];
    const float* inputs = (const float*)d_in[1];
    const float* ln1w   = (const float*)d_in[2];
    const float* ln1b   = (const float*)d_in[3];
    const float* ln2w   = (const float*)d_in[4];
    const float* ln2b   = (const float*)d_in[5];
    const float* Wq     = (const float*)d_in[6];
    const float* bq     = (const float*)d_in[7];
    const float* Wk     = (const float*)d_in[8];
    const float* bk     = (const float*)d_in[9];
    const float* Wv     = (const float*)d_in[10];
    const float* bv     = (const float*)d_in[11];
    float* out = (float*)d_out;
    char* ws = (char*)d_ws;

    unsigned char* LNh8 = (unsigned char*)ws;          // 4096x1024 fp8
    unsigned char* LNx8 = LNh8 + 4194304;              // 32768x1024 fp8
    unsigned char* Wq8  = LNx8 + 33554432;
    unsigned char* Wk8  = Wq8 + 1048576;
    unsigned char* Wv8  = Wk8 + 1048576;
    unsigned short* Qm  = (unsigned short*)(Wv8 + 1048576);   // 4096x1024 bf16
    unsigned short* Km  = Qm + 4194304;                // 32768x1024 bf16
    unsigned short* VtG = Km + 33554432;               // [b][h][128 d][4096 kv] bf16

    prep<<<dim3(9984), dim3(256), 0, stream>>>(
        hidden, inputs, ln1w, ln1b, ln2w, ln2b, Wq, Wk, Wv, LNh8, LNx8, Wq8, Wk8, Wv8);
    gemm256<<<dim3(1088), dim3(512), 0, stream>>>(
        LNx8, LNh8, Wk8, Wq8, bk, bv, bq, Km, VtG, Qm);
    attn_kernel<<<dim3(512), dim3(256), 0, stream>>>(Qm, Km, VtG, hidden, out);
}